// Round 1
// baseline (764.043 us; speedup 1.0000x reference)
//
#include <hip/hip_runtime.h>
#include <hip/hip_bf16.h>

// B=4, T=2048, D=1024, H=16, HD=64
#define Bsz 4
#define Tsz 2048
#define Dsz 1024
#define Hsz 16
#define HDsz 64

typedef __attribute__((ext_vector_type(8))) __bf16 bf16x8;
typedef __attribute__((ext_vector_type(4))) float f32x4;

#define DEVI static __device__ __forceinline__

DEVI unsigned short f2bf(float f) {
    union { float f; unsigned u; } x; x.f = f;
    unsigned u = x.u + 0x7fffu + ((x.u >> 16) & 1u);
    return (unsigned short)(u >> 16);
}

DEVI bf16x8 ld_bf8(const unsigned short* p) {
    return *reinterpret_cast<const bf16x8*>(p);
}

// ---------------------------------------------------------------------------
// Generic bf16 MFMA GEMM, 64x64 tile, 4 waves, 2x2 16x16x32 fragments/wave.
// A: row-major [M,K] (fp32 if ABF==0, bf16/ushort if ABF==1)
// B: row-major [K,N] fp32
// EPI==0: Cf[row*N+col] = acc + bias[col]  (fp32)
// EPI==1: QKV scatter: col<1024 -> Q[bh,t,hd]; <2048 -> K[bh,t,hd];
//         else V^T[bh,hd,t]   (all bf16)
// ---------------------------------------------------------------------------
template<int EPI, int ABF>
__global__ __launch_bounds__(256)
void gemm_bf16(const void* __restrict__ Aptr, const float* __restrict__ B,
               const float* __restrict__ bias,
               float* __restrict__ Cf,
               unsigned short* __restrict__ Qo,
               unsigned short* __restrict__ Ko,
               unsigned short* __restrict__ Vo,
               int M, int N, int K)
{
    constexpr int LDSS = 48;                       // row stride (ushort), 96B: 16B-aligned rows
    __shared__ unsigned short As[64][LDSS];
    __shared__ unsigned short Bs[64][LDSS];        // B stored transposed: Bs[n][k]

    const int tN = blockIdx.x, tM = blockIdx.y;
    const int t = threadIdx.x;
    const int l = t & 63, w = t >> 6;
    const int wm = w >> 1, wn = w & 1;
    const int lrow = l & 15, lk = l >> 4;

    f32x4 acc[2][2] = {};

    const int arow = t >> 2, acol = (t & 3) * 8;   // A stage: 64 rows x 32 k
    const int brow = t >> 3, bcol = (t & 7) * 8;   // B stage: 32 k x 64 n

    const float*          Agf = (const float*)Aptr          + (size_t)(tM*64 + arow) * K + acol;
    const unsigned short* Agh = (const unsigned short*)Aptr + (size_t)(tM*64 + arow) * K + acol;
    const float*          Bg  = B + (size_t)brow * N + (size_t)tN*64 + bcol;

    for (int ks = 0; ks < K; ks += 32) {
        __syncthreads();
        if (ABF) {
            *reinterpret_cast<uint4*>(&As[arow][acol]) =
                *reinterpret_cast<const uint4*>(Agh + ks);
        } else {
            const float4 f0 = *reinterpret_cast<const float4*>(Agf + ks);
            const float4 f1 = *reinterpret_cast<const float4*>(Agf + ks + 4);
            unsigned short tmp[8] = { f2bf(f0.x), f2bf(f0.y), f2bf(f0.z), f2bf(f0.w),
                                      f2bf(f1.x), f2bf(f1.y), f2bf(f1.z), f2bf(f1.w) };
            *reinterpret_cast<uint4*>(&As[arow][acol]) = *reinterpret_cast<uint4*>(tmp);
        }
        {
            const float4 f0 = *reinterpret_cast<const float4*>(Bg + (size_t)ks * N);
            const float4 f1 = *reinterpret_cast<const float4*>(Bg + (size_t)ks * N + 4);
            float v[8] = { f0.x, f0.y, f0.z, f0.w, f1.x, f1.y, f1.z, f1.w };
            #pragma unroll
            for (int i = 0; i < 8; ++i) Bs[bcol + i][brow] = f2bf(v[i]);
        }
        __syncthreads();

        bf16x8 a0 = ld_bf8(&As[wm*32 +      lrow][lk*8]);
        bf16x8 a1 = ld_bf8(&As[wm*32 + 16 + lrow][lk*8]);
        bf16x8 b0 = ld_bf8(&Bs[wn*32 +      lrow][lk*8]);
        bf16x8 b1 = ld_bf8(&Bs[wn*32 + 16 + lrow][lk*8]);
        acc[0][0] = __builtin_amdgcn_mfma_f32_16x16x32_bf16(a0, b0, acc[0][0], 0, 0, 0);
        acc[0][1] = __builtin_amdgcn_mfma_f32_16x16x32_bf16(a0, b1, acc[0][1], 0, 0, 0);
        acc[1][0] = __builtin_amdgcn_mfma_f32_16x16x32_bf16(a1, b0, acc[1][0], 0, 0, 0);
        acc[1][1] = __builtin_amdgcn_mfma_f32_16x16x32_bf16(a1, b1, acc[1][1], 0, 0, 0);
    }

    #pragma unroll
    for (int fm = 0; fm < 2; ++fm)
    #pragma unroll
    for (int fn = 0; fn < 2; ++fn)
    #pragma unroll
    for (int r = 0; r < 4; ++r) {
        const int row = tM*64 + wm*32 + fm*16 + lk*4 + r;
        const int col = tN*64 + wn*32 + fn*16 + lrow;
        const float v = acc[fm][fn][r] + bias[col];
        if (EPI == 0) {
            Cf[(size_t)row * N + col] = v;
        } else {
            const int which = col >> 10;
            const int h  = (col & 1023) >> 6;
            const int hd = col & 63;
            const int b  = row >> 11;
            const int tt = row & 2047;
            const int bh = b * Hsz + h;
            const unsigned short bv = f2bf(v);
            if (which == 0)      Qo[((size_t)bh * Tsz + tt) * HDsz + hd] = bv;
            else if (which == 1) Ko[((size_t)bh * Tsz + tt) * HDsz + hd] = bv;
            else                 Vo[((size_t)bh * HDsz + hd) * Tsz + tt] = bv;
        }
    }
}

// ---------------------------------------------------------------------------
// Flash attention (causal). 1 block = (b,h, 64 q-rows); 4 waves x 16 q-rows.
// Q,K: [B*H, T, 64] bf16.  Vt: [B*H, 64, T] bf16.  AO: [B, T, D] bf16.
// ---------------------------------------------------------------------------
__global__ __launch_bounds__(256)
void attn_kernel(const unsigned short* __restrict__ Q,
                 const unsigned short* __restrict__ K,
                 const unsigned short* __restrict__ Vt,
                 unsigned short* __restrict__ AO)
{
    __shared__ unsigned short Plds[4][16][40];     // per-wave P tile (16q x 32kv)
    const int bh = blockIdx.y;
    const int t  = threadIdx.x;
    const int w  = t >> 6, l = t & 63;
    const int lrow = l & 15, lk = l >> 4;
    const int qbase = blockIdx.x * 64 + w * 16;

    const unsigned short* Qh = Q  + (size_t)bh * Tsz * HDsz;
    const unsigned short* Kh = K  + (size_t)bh * Tsz * HDsz;
    const unsigned short* Vh = Vt + (size_t)bh * HDsz * Tsz;

    const bf16x8 q0 = ld_bf8(&Qh[(qbase + lrow) * HDsz + lk*8]);
    const bf16x8 q1 = ld_bf8(&Qh[(qbase + lrow) * HDsz + 32 + lk*8]);

    f32x4 o[4] = {};
    float m[4], lsum[4];
    #pragma unroll
    for (int r = 0; r < 4; ++r) { m[r] = -1e30f; lsum[r] = 0.f; }

    const int nkv = qbase / 32 + 1;
    for (int kb = 0; kb < nkv; ++kb) {
        const int kv0 = kb * 32;
        const f32x4 zero = {};
        const bf16x8 k00 = ld_bf8(&Kh[(kv0 +      lrow) * HDsz +      lk*8]);
        const bf16x8 k01 = ld_bf8(&Kh[(kv0 +      lrow) * HDsz + 32 + lk*8]);
        const bf16x8 k10 = ld_bf8(&Kh[(kv0 + 16 + lrow) * HDsz +      lk*8]);
        const bf16x8 k11 = ld_bf8(&Kh[(kv0 + 16 + lrow) * HDsz + 32 + lk*8]);
        f32x4 s0 = __builtin_amdgcn_mfma_f32_16x16x32_bf16(q0, k00, zero, 0, 0, 0);
        s0       = __builtin_amdgcn_mfma_f32_16x16x32_bf16(q1, k01, s0,   0, 0, 0);
        f32x4 s1 = __builtin_amdgcn_mfma_f32_16x16x32_bf16(q0, k10, zero, 0, 0, 0);
        s1       = __builtin_amdgcn_mfma_f32_16x16x32_bf16(q1, k11, s1,   0, 0, 0);

        const bool needmask = (kv0 + 31 > qbase);
        #pragma unroll
        for (int r = 0; r < 4; ++r) {
            s0[r] *= 0.125f; s1[r] *= 0.125f;        // 1/sqrt(64)
            if (needmask) {
                const int qr = qbase + lk*4 + r;
                if (kv0 +      lrow > qr) s0[r] = -1e30f;
                if (kv0 + 16 + lrow > qr) s1[r] = -1e30f;
            }
        }

        float mx[4];
        #pragma unroll
        for (int r = 0; r < 4; ++r) mx[r] = fmaxf(s0[r], s1[r]);
        #pragma unroll
        for (int d = 1; d < 16; d <<= 1) {
            #pragma unroll
            for (int r = 0; r < 4; ++r) mx[r] = fmaxf(mx[r], __shfl_xor(mx[r], d));
        }

        float p0[4], p1[4], rs[4];
        #pragma unroll
        for (int r = 0; r < 4; ++r) {
            const float mn    = fmaxf(m[r], mx[r]);
            const float alpha = __expf(m[r] - mn);
            p0[r] = __expf(s0[r] - mn);
            p1[r] = __expf(s1[r] - mn);
            rs[r] = p0[r] + p1[r];
            lsum[r] *= alpha;
            m[r] = mn;
            #pragma unroll
            for (int c = 0; c < 4; ++c) o[c][r] *= alpha;
        }
        #pragma unroll
        for (int d = 1; d < 16; d <<= 1) {
            #pragma unroll
            for (int r = 0; r < 4; ++r) rs[r] += __shfl_xor(rs[r], d);
        }
        #pragma unroll
        for (int r = 0; r < 4; ++r) lsum[r] += rs[r];

        // acc-layout P -> A-fragment layout via per-wave LDS round-trip
        #pragma unroll
        for (int r = 0; r < 4; ++r) {
            Plds[w][lk*4 + r][lrow]      = f2bf(p0[r]);
            Plds[w][lk*4 + r][16 + lrow] = f2bf(p1[r]);
        }
        const bf16x8 pa = ld_bf8(&Plds[w][lrow][lk*8]);
        #pragma unroll
        for (int c = 0; c < 4; ++c) {
            const bf16x8 vb = ld_bf8(&Vh[(size_t)(c*16 + lrow) * Tsz + kv0 + lk*8]);
            o[c] = __builtin_amdgcn_mfma_f32_16x16x32_bf16(pa, vb, o[c], 0, 0, 0);
        }
    }

    const int b = bh >> 4, h = bh & 15;
    #pragma unroll
    for (int c = 0; c < 4; ++c)
    #pragma unroll
    for (int r = 0; r < 4; ++r) {
        const int tt = qbase + lk*4 + r;
        const int hd = c*16 + lrow;
        const float v = o[c][r] / lsum[r];
        AO[((size_t)b * Tsz + tt) * Dsz + h * HDsz + hd] = f2bf(v);
    }
}

extern "C" void kernel_launch(void* const* d_in, const int* in_sizes, int n_in,
                              void* d_out, int out_size, void* d_ws, size_t ws_size,
                              hipStream_t stream)
{
    (void)in_sizes; (void)n_in; (void)out_size; (void)ws_size;

    const float* x      = (const float*)d_in[0];
    const float* qkv_w  = (const float*)d_in[1];
    const float* qkv_b  = (const float*)d_in[2];
    const float* proj_w = (const float*)d_in[3];
    const float* proj_b = (const float*)d_in[4];
    float* out = (float*)d_out;

    char* ws = (char*)d_ws;
    const size_t SZ = (size_t)Bsz * Hsz * Tsz * HDsz * sizeof(unsigned short); // 16 MB
    unsigned short* Qb = (unsigned short*)(ws);
    unsigned short* Kb = (unsigned short*)(ws + SZ);
    unsigned short* Vt = (unsigned short*)(ws + 2*SZ);
    unsigned short* AO = (unsigned short*)(ws + 3*SZ);

    const int M = Bsz * Tsz;   // 8192

    // 1) QKV projection: [8192,1024] x [1024,3072] -> Q/K/V^T (bf16)
    gemm_bf16<1, 0><<<dim3((3*Dsz)/64, M/64), 256, 0, stream>>>(
        x, qkv_w, qkv_b, nullptr, Qb, Kb, Vt, M, 3*Dsz, Dsz);

    // 2) causal flash attention -> AO [B,T,D] bf16
    attn_kernel<<<dim3(Tsz/64, Bsz*Hsz), 256, 0, stream>>>(Qb, Kb, Vt, AO);

    // 3) output projection: [8192,1024] x [1024,1024] + bias -> fp32 out
    gemm_bf16<0, 1><<<dim3(Dsz/64, M/64), 256, 0, stream>>>(
        AO, proj_w, proj_b, out, nullptr, nullptr, nullptr, M, Dsz, Dsz);
}

// Round 2
// 296.985 us; speedup vs baseline: 2.5727x; 2.5727x over previous
//
#include <hip/hip_runtime.h>
#include <hip/hip_bf16.h>

// B=4, T=2048, D=1024, H=16, HD=64
#define Bsz 4
#define Tsz 2048
#define Dsz 1024
#define Hsz 16
#define HDsz 64

typedef __attribute__((ext_vector_type(8))) __bf16 bf16x8;
typedef __attribute__((ext_vector_type(4))) float f32x4;
typedef unsigned short u16;
typedef unsigned int u32;

#define DEVI static __device__ __forceinline__

DEVI u16 f2bf(float f) {
    union { float f; u32 u; } x; x.f = f;
    u32 u = x.u + 0x7fffu + ((x.u >> 16) & 1u);
    return (u16)(u >> 16);
}
DEVI bf16x8 ld_bf8(const u16* p) { return *reinterpret_cast<const bf16x8*>(p); }

// async global->LDS, 16B per lane. lds ptr must be wave-uniform (HW writes
// base + lane*16); global ptr is per-lane.
DEVI void gll16(const u16* g, u16* lds) {
    __builtin_amdgcn_global_load_lds(
        (const __attribute__((address_space(1))) u32*)g,
        (__attribute__((address_space(3))) u32*)lds, 16, 0, 0);
}

// ---------------------------------------------------------------------------
// Transpose+convert: W[K][N] fp32 -> WT[N][K] bf16. 64x64 tiles.
// grid (N/64, K/64), 256 threads.
// ---------------------------------------------------------------------------
__global__ __launch_bounds__(256)
void transpose_w(const float* __restrict__ W, u16* __restrict__ WT, int K, int N)
{
    __shared__ float tile[64][65];
    const int n0 = blockIdx.x * 64, k0 = blockIdx.y * 64;
    const int t = threadIdx.x;
    #pragma unroll
    for (int i = 0; i < 4; ++i) {
        const int idx = i*256 + t;              // float4 index
        const int row = idx >> 4, c4 = (idx & 15) * 4;
        const float4 v = *(const float4*)(W + (size_t)(k0 + row)*N + n0 + c4);
        tile[row][c4+0] = v.x; tile[row][c4+1] = v.y;
        tile[row][c4+2] = v.z; tile[row][c4+3] = v.w;
    }
    __syncthreads();
    #pragma unroll
    for (int j = 0; j < 2; ++j) {
        const int idx = j*256 + t;
        const int nr = idx >> 3, kc = (idx & 7) * 8;
        u16 h[8];
        #pragma unroll
        for (int e = 0; e < 8; ++e) h[e] = f2bf(tile[kc + e][nr]);
        *(uint4*)(WT + (size_t)(n0 + nr)*K + k0 + kc) = *(uint4*)h;
    }
}

// ---------------------------------------------------------------------------
// 128x128 bf16 MFMA GEMM (m97 structure), BK=32, 4 waves, 4x4 frags/wave.
// A: [M,K] fp32 (AGLL=0, reg-staged+converted) or bf16 (AGLL=1, global_load_lds)
// Bt: [N,K] bf16 (pre-transposed weights), staged via global_load_lds.
// EPI==0: Cf[row*N+col] = acc + bias[col] (fp32)
// EPI==1: QKV scatter -> Q/K [bh,t,hd], V^T [bh,hd,t] (bf16)
// ---------------------------------------------------------------------------
template<int EPI, int AGLL>
__global__ __launch_bounds__(256)
void gemm128(const void* __restrict__ Aptr, const u16* __restrict__ Bt,
             const float* __restrict__ bias, float* __restrict__ Cf,
             u16* __restrict__ Qo, u16* __restrict__ Ko, u16* __restrict__ Vo,
             int M, int N, int K)
{
    __shared__ u16 As[128][32];
    __shared__ u16 Bs[128][32];
    const int tN = blockIdx.x, tM = blockIdx.y;
    const int t = threadIdx.x, l = t & 63, w = t >> 6;
    const int wm = w >> 1, wn = w & 1;
    const int lrow = l & 15, lk = l >> 4;

    f32x4 acc[4][4] = {};

    for (int ks = 0; ks < K; ks += 32) {
        __syncthreads();                       // LDS reads of prev iter done
        if (AGLL) {
            const u16* Ab = (const u16*)Aptr;
            #pragma unroll
            for (int r = 0; r < 2; ++r) {
                const int c = r*256 + t;
                gll16(Ab + (size_t)(tM*128 + (c>>2))*K + ks + (c&3)*8,
                      (u16*)As + (size_t)(r*256 + (t & 192))*8);
            }
        } else {
            const float* Af = (const float*)Aptr;
            #pragma unroll
            for (int i = 0; i < 4; ++i) {
                const int idx = i*256 + t;
                const int row = idx >> 3, c4 = (idx & 7)*4;
                const float4 v = *(const float4*)(Af + (size_t)(tM*128 + row)*K + ks + c4);
                u16 h[4] = { f2bf(v.x), f2bf(v.y), f2bf(v.z), f2bf(v.w) };
                *(ushort4*)(&As[row][c4]) = *(ushort4*)h;
            }
        }
        #pragma unroll
        for (int r = 0; r < 2; ++r) {
            const int c = r*256 + t;
            gll16(Bt + (size_t)(tN*128 + (c>>2))*K + ks + (c&3)*8,
                  (u16*)Bs + (size_t)(r*256 + (t & 192))*8);
        }
        __syncthreads();                       // staging visible (drains vmcnt)

        bf16x8 a[4], bb[4];
        #pragma unroll
        for (int i = 0; i < 4; ++i) a[i]  = ld_bf8(&As[wm*64 + i*16 + lrow][lk*8]);
        #pragma unroll
        for (int j = 0; j < 4; ++j) bb[j] = ld_bf8(&Bs[wn*64 + j*16 + lrow][lk*8]);
        #pragma unroll
        for (int i = 0; i < 4; ++i)
        #pragma unroll
        for (int j = 0; j < 4; ++j)
            acc[i][j] = __builtin_amdgcn_mfma_f32_16x16x32_bf16(a[i], bb[j], acc[i][j], 0, 0, 0);
    }

    #pragma unroll
    for (int i = 0; i < 4; ++i)
    #pragma unroll
    for (int j = 0; j < 4; ++j)
    #pragma unroll
    for (int r = 0; r < 4; ++r) {
        const int row = tM*128 + wm*64 + i*16 + lk*4 + r;
        const int col = tN*128 + wn*64 + j*16 + lrow;
        const float v = acc[i][j][r] + bias[col];
        if (EPI == 0) {
            Cf[(size_t)row * N + col] = v;
        } else {
            const int which = col >> 10;
            const int h  = (col & 1023) >> 6;
            const int hd = col & 63;
            const int b  = row >> 11;
            const int tt = row & 2047;
            const int bh = b * Hsz + h;
            const u16 bv = f2bf(v);
            if (which == 0)      Qo[((size_t)bh * Tsz + tt) * HDsz + hd] = bv;
            else if (which == 1) Ko[((size_t)bh * Tsz + tt) * HDsz + hd] = bv;
            else                 Vo[((size_t)bh * HDsz + hd) * Tsz + tt] = bv;
        }
    }
}

// ---------------------------------------------------------------------------
// Flash attention v2 (causal). Block = 4 waves; wave w owns 32 q-rows.
// Grid (T/128, B*H), heavy q-tiles dispatched first.
// Swapped QK^T: s^T = mfma(K,Q) -> per-lane full score row (in-lane softmax).
// PV double-swapped: o^T = mfma(V^T, P) -> q stays on lane index.
// K/V tiles (64 kv) double-buffered in LDS via global_load_lds with
// XOR-swizzled SOURCE addresses (linear LDS dest) + swizzled ds_read.
// ---------------------------------------------------------------------------
__global__ __launch_bounds__(256, 3)
void attn2(const u16* __restrict__ Q, const u16* __restrict__ K,
           const u16* __restrict__ Vt, u16* __restrict__ AO)
{
    __shared__ u16 KV[2][2][64][64];   // [buf][K/V][row][col], 32 KB
    __shared__ u16 Pl[4][32][64];      // per-wave P (swizzled), 16 KB

    const int bh = blockIdx.y;
    const int qt = (gridDim.x - 1) - blockIdx.x;   // heavy first
    const int t = threadIdx.x, w = t >> 6, l = t & 63;
    const int lrow = l & 15, lk = l >> 4;
    const int qw = qt*128 + w*32;
    const int qwmax = qw + 31;
    const int swz = lrow & 7;

    const u16* Qh = Q  + (size_t)bh * Tsz * HDsz;
    const u16* Kh = K  + (size_t)bh * Tsz * HDsz;
    const u16* Vh = Vt + (size_t)bh * HDsz * Tsz;

    // hoisted Q fragments (B-operand: col = q on lane)
    bf16x8 qf[2][2];
    #pragma unroll
    for (int f = 0; f < 2; ++f)
    #pragma unroll
    for (int kh = 0; kh < 2; ++kh)
        qf[f][kh] = ld_bf8(&Qh[(size_t)(qw + f*16 + lrow)*HDsz + kh*32 + lk*8]);

    f32x4 o[2][4] = {};
    float m[2] = {-1e30f, -1e30f}, lsum[2] = {0.f, 0.f};

    const int ntile = 2*qt + 2;
    int cur = 0;

    // stage tile 0
    #pragma unroll
    for (int rr = 0; rr < 2; ++rr) {
        const int c = rr*256 + t;
        const int row = c >> 3, gc = (c & 7) ^ (row & 7);
        gll16(Kh + (size_t)row*HDsz + gc*8,
              &KV[0][0][0][0] + (size_t)(rr*256 + (t & 192))*8);
        gll16(Vh + (size_t)row*Tsz + gc*8,
              &KV[0][1][0][0] + (size_t)(rr*256 + (t & 192))*8);
    }
    __syncthreads();

    for (int tk = 0; tk < ntile; ++tk) {
        if (tk + 1 < ntile) {        // prefetch next tile into other buffer
            const int nkv = (tk + 1) * 64;
            #pragma unroll
            for (int rr = 0; rr < 2; ++rr) {
                const int c = rr*256 + t;
                const int row = c >> 3, gc = (c & 7) ^ (row & 7);
                gll16(Kh + (size_t)(nkv + row)*HDsz + gc*8,
                      &KV[cur^1][0][0][0] + (size_t)(rr*256 + (t & 192))*8);
                gll16(Vh + (size_t)row*Tsz + nkv + gc*8,
                      &KV[cur^1][1][0][0] + (size_t)(rr*256 + (t & 192))*8);
            }
        }
        const int kv0 = tk * 64;
        if (kv0 <= qwmax) {
            const u16 (*Ks)[64] = KV[cur][0];
            const u16 (*Vs)[64] = KV[cur][1];
            const bool fullc    = (kv0 + 63 <= qwmax);  // c>=2 / kvh=1 active
            const bool needmask = (kv0 + 64 > qw);

            f32x4 s[2][4];
            #pragma unroll
            for (int c = 0; c < 4; ++c) {
                if (c >= 2 && !fullc) continue;
                const bf16x8 k0 = ld_bf8(&Ks[c*16 + lrow][((0 + lk) ^ swz) * 8]);
                const bf16x8 k1 = ld_bf8(&Ks[c*16 + lrow][((4 + lk) ^ swz) * 8]);
                #pragma unroll
                for (int f = 0; f < 2; ++f) {
                    f32x4 z = {};
                    z = __builtin_amdgcn_mfma_f32_16x16x32_bf16(k0, qf[f][0], z, 0, 0, 0);
                    z = __builtin_amdgcn_mfma_f32_16x16x32_bf16(k1, qf[f][1], z, 0, 0, 0);
                    s[f][c] = z;
                }
            }
            #pragma unroll
            for (int f = 0; f < 2; ++f) {
                const int q = qw + f*16 + lrow;
                float mx = -1e30f;
                #pragma unroll
                for (int c = 0; c < 4; ++c) {
                    if (c >= 2 && !fullc) continue;
                    #pragma unroll
                    for (int r = 0; r < 4; ++r) {
                        float v = s[f][c][r] * 0.125f;       // 1/sqrt(64)
                        if (needmask && (kv0 + c*16 + lk*4 + r > q)) v = -1e30f;
                        s[f][c][r] = v;
                        mx = fmaxf(mx, v);
                    }
                }
                mx = fmaxf(mx, __shfl_xor(mx, 16));
                mx = fmaxf(mx, __shfl_xor(mx, 32));
                const float mn = fmaxf(m[f], mx);
                const float al = __expf(m[f] - mn);
                m[f] = mn;
                float ps = 0.f;
                #pragma unroll
                for (int c = 0; c < 4; ++c) {
                    if (c >= 2 && !fullc) continue;
                    #pragma unroll
                    for (int r = 0; r < 4; ++r) {
                        const float p = __expf(s[f][c][r] - mn);
                        s[f][c][r] = p;
                        ps += p;
                    }
                }
                ps += __shfl_xor(ps, 16);
                ps += __shfl_xor(ps, 32);
                lsum[f] = lsum[f]*al + ps;
                #pragma unroll
                for (int c = 0; c < 4; ++c)
                #pragma unroll
                for (int r = 0; r < 4; ++r) o[f][c][r] *= al;
                // P^T in-lane -> LDS (swizzled chunks), 4 consecutive kv per write
                #pragma unroll
                for (int c = 0; c < 4; ++c) {
                    if (c >= 2 && !fullc) continue;
                    u16 pk[4] = { f2bf(s[f][c][0]), f2bf(s[f][c][1]),
                                  f2bf(s[f][c][2]), f2bf(s[f][c][3]) };
                    const int chunk = (c*2 + (lk >> 1)) ^ swz;
                    *(ushort4*)(&Pl[w][f*16 + lrow][chunk*8 + (lk & 1)*4]) = *(ushort4*)pk;
                }
            }
            // PV: o^T += mfma(V^T, P)
            #pragma unroll
            for (int kvh = 0; kvh < 2; ++kvh) {
                if (kvh == 1 && !fullc) continue;
                const bf16x8 pb0 = ld_bf8(&Pl[w][ 0 + lrow][((kvh*4 + lk) ^ swz)*8]);
                const bf16x8 pb1 = ld_bf8(&Pl[w][16 + lrow][((kvh*4 + lk) ^ swz)*8]);
                #pragma unroll
                for (int chd = 0; chd < 4; ++chd) {
                    const bf16x8 va = ld_bf8(&Vs[chd*16 + lrow][((kvh*4 + lk) ^ swz)*8]);
                    o[0][chd] = __builtin_amdgcn_mfma_f32_16x16x32_bf16(va, pb0, o[0][chd], 0, 0, 0);
                    o[1][chd] = __builtin_amdgcn_mfma_f32_16x16x32_bf16(va, pb1, o[1][chd], 0, 0, 0);
                }
            }
        }
        __syncthreads();   // drains prefetch + protects buffer swap
        cur ^= 1;
    }

    const int b = bh >> 4, h = bh & 15;
    #pragma unroll
    for (int f = 0; f < 2; ++f) {
        const float rl = 1.0f / lsum[f];
        #pragma unroll
        for (int chd = 0; chd < 4; ++chd) {
            u16 ov[4] = { f2bf(o[f][chd][0]*rl), f2bf(o[f][chd][1]*rl),
                          f2bf(o[f][chd][2]*rl), f2bf(o[f][chd][3]*rl) };
            *(ushort4*)(AO + ((size_t)(b*Tsz + qw + f*16 + lrow))*Dsz
                           + h*HDsz + chd*16 + lk*4) = *(ushort4*)ov;
        }
    }
}

extern "C" void kernel_launch(void* const* d_in, const int* in_sizes, int n_in,
                              void* d_out, int out_size, void* d_ws, size_t ws_size,
                              hipStream_t stream)
{
    (void)in_sizes; (void)n_in; (void)out_size; (void)ws_size;

    const float* x      = (const float*)d_in[0];
    const float* qkv_w  = (const float*)d_in[1];
    const float* qkv_b  = (const float*)d_in[2];
    const float* proj_w = (const float*)d_in[3];
    const float* proj_b = (const float*)d_in[4];
    float* out = (float*)d_out;

    char* ws = (char*)d_ws;
    const size_t SZ = (size_t)Bsz * Hsz * Tsz * HDsz * sizeof(u16);  // 16 MB
    // R0: WQKVT (6.3MB) during QKV GEMM, then AO (16.8MB) after.
    // R1: Q during QKV+attn, then WPT (2.1MB) for proj.
    u16* R0 = (u16*)(ws);
    u16* Qb = (u16*)(ws + SZ);
    u16* Kb = (u16*)(ws + 2*SZ);
    u16* Vt = (u16*)(ws + 3*SZ);
    u16* WQKVT = R0;
    u16* AO    = R0;
    u16* WPT   = Qb;

    const int M = Bsz * Tsz;   // 8192

    // 1) qkv_w [1024][3072] -> WQKVT [3072][1024] bf16
    transpose_w<<<dim3(3*Dsz/64, Dsz/64), 256, 0, stream>>>(qkv_w, WQKVT, Dsz, 3*Dsz);
    // 2) QKV projection -> Q/K/V^T bf16
    gemm128<1, 0><<<dim3(3*Dsz/128, M/128), 256, 0, stream>>>(
        x, WQKVT, qkv_b, nullptr, Qb, Kb, Vt, M, 3*Dsz, Dsz);
    // 3) causal flash attention -> AO (overwrites WQKVT region; it is dead)
    attn2<<<dim3(Tsz/128, Bsz*Hsz), 256, 0, stream>>>(Qb, Kb, Vt, AO);
    // 4) proj_w [1024][1024] -> WPT bf16 (Q region; Q is dead)
    transpose_w<<<dim3(Dsz/64, Dsz/64), 256, 0, stream>>>(proj_w, WPT, Dsz, Dsz);
    // 5) output projection -> fp32 out
    gemm128<0, 1><<<dim3(Dsz/128, M/128), 256, 0, stream>>>(
        AO, WPT, proj_b, out, nullptr, nullptr, nullptr, M, Dsz, Dsz);
}

// Round 3
// 247.784 us; speedup vs baseline: 3.0835x; 1.1986x over previous
//
#include <hip/hip_runtime.h>
#include <hip/hip_bf16.h>

// B=4, T=2048, D=1024, H=16, HD=64
#define Bsz 4
#define Tsz 2048
#define Dsz 1024
#define Hsz 16
#define HDsz 64

typedef __attribute__((ext_vector_type(8))) __bf16 bf16x8;
typedef __attribute__((ext_vector_type(4))) __bf16 bf16x4;
typedef __attribute__((ext_vector_type(4))) float f32x4;
typedef __attribute__((ext_vector_type(2))) float f32x2;
typedef unsigned short u16;
typedef unsigned int u32;

#define DEVI static __device__ __forceinline__

DEVI u16 f2bf(float f) {
    __bf16 h = (__bf16)f;
    union { __bf16 h; u16 u; } c; c.h = h; return c.u;
}
DEVI bf16x8 ld_bf8(const u16* p) { return *reinterpret_cast<const bf16x8*>(p); }

// async global->LDS, 16B per lane. lds dest is wave-uniform base + lane*16.
DEVI void gll16(const u16* g, u16* lds) {
    __builtin_amdgcn_global_load_lds(
        (const __attribute__((address_space(1))) u32*)g,
        (__attribute__((address_space(3))) u32*)lds, 16, 0, 0);
}

// K=16 MFMA: acc(16x16, f32) += A(16x16 bf16) * B(16x16 bf16).
// A,B are 4 bf16 in 2 VGPRs (passed as f32x2 bit-pattern).
DEVI void mfma16(f32x4& c, f32x2 a, f32x2 b) {
    asm("v_mfma_f32_16x16x16_bf16 %0, %1, %2, %0" : "+v"(c) : "v"(a), "v"(b));
}

// ---------------------------------------------------------------------------
// Transpose+convert: W[K][N] fp32 -> WT[N][K] bf16. 64x64 tiles.
// ---------------------------------------------------------------------------
__global__ __launch_bounds__(256)
void transpose_w(const float* __restrict__ W, u16* __restrict__ WT, int K, int N)
{
    __shared__ float tile[64][65];
    const int n0 = blockIdx.x * 64, k0 = blockIdx.y * 64;
    const int t = threadIdx.x;
    #pragma unroll
    for (int i = 0; i < 4; ++i) {
        const int idx = i*256 + t;
        const int row = idx >> 4, c4 = (idx & 15) * 4;
        const float4 v = *(const float4*)(W + (size_t)(k0 + row)*N + n0 + c4);
        tile[row][c4+0] = v.x; tile[row][c4+1] = v.y;
        tile[row][c4+2] = v.z; tile[row][c4+3] = v.w;
    }
    __syncthreads();
    #pragma unroll
    for (int j = 0; j < 2; ++j) {
        const int idx = j*256 + t;
        const int nr = idx >> 3, kc = (idx & 7) * 8;
        u16 h[8];
        #pragma unroll
        for (int e = 0; e < 8; ++e) h[e] = f2bf(tile[kc + e][nr]);
        *(uint4*)(WT + (size_t)(n0 + nr)*K + k0 + kc) = *(uint4*)h;
    }
}

// ---------------------------------------------------------------------------
// 128x128 bf16 MFMA GEMM, BK=32, 4 waves, 4x4 frags/wave.
// LDS XOR-swizzled (chunk ^= (row>>1)&3): linear gll dest, pre-swizzled src.
// ---------------------------------------------------------------------------
template<int EPI, int AGLL>
__global__ __launch_bounds__(256)
void gemm128(const void* __restrict__ Aptr, const u16* __restrict__ Bt,
             const float* __restrict__ bias, float* __restrict__ Cf,
             u16* __restrict__ Qo, u16* __restrict__ Ko, u16* __restrict__ Vo,
             int M, int N, int K)
{
    __shared__ u16 As[128][32];
    __shared__ u16 Bs[128][32];
    const int tN = blockIdx.x, tM = blockIdx.y;
    const int t = threadIdx.x, l = t & 63, w = t >> 6;
    const int wm = w >> 1, wn = w & 1;
    const int lrow = l & 15, lk = l >> 4;

    f32x4 acc[4][4] = {};

    for (int ks = 0; ks < K; ks += 32) {
        __syncthreads();
        if (AGLL) {
            const u16* Ab = (const u16*)Aptr;
            #pragma unroll
            for (int r = 0; r < 2; ++r) {
                const int c = r*256 + t;
                const int row = c >> 2, ch = (c & 3) ^ ((row >> 1) & 3);
                gll16(Ab + (size_t)(tM*128 + row)*K + ks + ch*8,
                      (u16*)As + (size_t)(r*256 + (t & 192))*8);
            }
        } else {
            const float* Af = (const float*)Aptr;
            #pragma unroll
            for (int i = 0; i < 4; ++i) {
                const int idx = i*256 + t;
                const int row = idx >> 3, c4 = (idx & 7)*4;
                const float4 v = *(const float4*)(Af + (size_t)(tM*128 + row)*K + ks + c4);
                u16 h[4] = { f2bf(v.x), f2bf(v.y), f2bf(v.z), f2bf(v.w) };
                const int pcol = (((c4 >> 3) ^ ((row >> 1) & 3)) << 3) + (c4 & 7);
                *(ushort4*)(&As[row][pcol]) = *(ushort4*)h;
            }
        }
        #pragma unroll
        for (int r = 0; r < 2; ++r) {
            const int c = r*256 + t;
            const int row = c >> 2, ch = (c & 3) ^ ((row >> 1) & 3);
            gll16(Bt + (size_t)(tN*128 + row)*K + ks + ch*8,
                  (u16*)Bs + (size_t)(r*256 + (t & 192))*8);
        }
        __syncthreads();

        bf16x8 a[4], bb[4];
        #pragma unroll
        for (int i = 0; i < 4; ++i) {
            const int ar = wm*64 + i*16 + lrow;
            a[i] = ld_bf8(&As[ar][(lk ^ ((ar >> 1) & 3)) * 8]);
        }
        #pragma unroll
        for (int j = 0; j < 4; ++j) {
            const int br = wn*64 + j*16 + lrow;
            bb[j] = ld_bf8(&Bs[br][(lk ^ ((br >> 1) & 3)) * 8]);
        }
        __builtin_amdgcn_s_setprio(1);
        #pragma unroll
        for (int i = 0; i < 4; ++i)
        #pragma unroll
        for (int j = 0; j < 4; ++j)
            acc[i][j] = __builtin_amdgcn_mfma_f32_16x16x32_bf16(a[i], bb[j], acc[i][j], 0, 0, 0);
        __builtin_amdgcn_s_setprio(0);
    }

    #pragma unroll
    for (int i = 0; i < 4; ++i)
    #pragma unroll
    for (int j = 0; j < 4; ++j)
    #pragma unroll
    for (int r = 0; r < 4; ++r) {
        const int row = tM*128 + wm*64 + i*16 + lk*4 + r;
        const int col = tN*128 + wn*64 + j*16 + lrow;
        const float v = acc[i][j][r] + bias[col];
        if (EPI == 0) {
            Cf[(size_t)row * N + col] = v;
        } else {
            const int which = col >> 10;
            const int h  = (col & 1023) >> 6;
            const int hd = col & 63;
            const int b  = row >> 11;
            const int tt = row & 2047;
            const int bh = b * Hsz + h;
            const u16 bv = f2bf(v);
            if (which == 0)      Qo[((size_t)bh * Tsz + tt) * HDsz + hd] = bv;
            else if (which == 1) Ko[((size_t)bh * Tsz + tt) * HDsz + hd] = bv;
            else                 Vo[((size_t)bh * HDsz + hd) * Tsz + tt] = bv;
        }
    }
}

// ---------------------------------------------------------------------------
// Flash attention v3 (causal). 4 waves x 32 q-rows; KVBLK=64, double-buffered.
// LDS = 32 KB (no P buffer): swapped QK^T leaves P^T in the exact B-fragment
// layout of v_mfma_f32_16x16x16_bf16, so PV consumes P from registers.
// Defer-max (THR=8 scaled = 64 raw). Balanced heavy/light qt pairing.
// ---------------------------------------------------------------------------
__global__ __launch_bounds__(256, 4)
void attn3(const u16* __restrict__ Q, const u16* __restrict__ K,
           const u16* __restrict__ Vt, u16* __restrict__ AO)
{
    __shared__ u16 KV[2][2][64][64];   // [buf][K/V][row][col], 32 KB

    const int bh = blockIdx.y;
    const int xx = blockIdx.x;
    const int qt = (xx & 1) ? (xx >> 1) : ((int)gridDim.x - 1 - (xx >> 1));
    const int t = threadIdx.x, w = t >> 6, l = t & 63;
    const int lrow = l & 15, lk = l >> 4;
    const int qw = qt*128 + w*32;
    const int qwmax = qw + 31;
    const int swz = lrow & 7;

    const u16* Qh = Q  + (size_t)bh * Tsz * HDsz;
    const u16* Kh = K  + (size_t)bh * Tsz * HDsz;
    const u16* Vh = Vt + (size_t)bh * HDsz * Tsz;

    bf16x8 qf[2][2];
    #pragma unroll
    for (int f = 0; f < 2; ++f)
    #pragma unroll
    for (int kh = 0; kh < 2; ++kh)
        qf[f][kh] = ld_bf8(&Qh[(size_t)(qw + f*16 + lrow)*HDsz + kh*32 + lk*8]);

    f32x4 o[2][4] = {};
    float m[2] = {-3e38f, -3e38f}, lsum[2] = {0.f, 0.f};

    const int ntile = 2*qt + 2;
    int cur = 0;

    // stage tile 0
    #pragma unroll
    for (int rr = 0; rr < 2; ++rr) {
        const int c = rr*256 + t;
        const int row = c >> 3, gc = (c & 7) ^ (row & 7);
        gll16(Kh + (size_t)row*HDsz + gc*8,
              &KV[0][0][0][0] + (size_t)(rr*256 + (t & 192))*8);
        gll16(Vh + (size_t)row*Tsz + gc*8,
              &KV[0][1][0][0] + (size_t)(rr*256 + (t & 192))*8);
    }
    __syncthreads();

    for (int tk = 0; tk < ntile; ++tk) {
        if (tk + 1 < ntile) {
            const int nkv = (tk + 1) * 64;
            #pragma unroll
            for (int rr = 0; rr < 2; ++rr) {
                const int c = rr*256 + t;
                const int row = c >> 3, gc = (c & 7) ^ (row & 7);
                gll16(Kh + (size_t)(nkv + row)*HDsz + gc*8,
                      &KV[cur^1][0][0][0] + (size_t)(rr*256 + (t & 192))*8);
                gll16(Vh + (size_t)row*Tsz + nkv + gc*8,
                      &KV[cur^1][1][0][0] + (size_t)(rr*256 + (t & 192))*8);
            }
        }
        const int kv0 = tk * 64;
        if (kv0 <= qwmax) {
            const u16 (*Ks)[64] = KV[cur][0];
            const u16 (*Vs)[64] = KV[cur][1];
            const bool fullc    = (kv0 + 63 <= qwmax);
            const bool needmask = (kv0 + 63 > qw);

            // QK^T (swapped): s[f][c][r] = S^T[kv=kv0+c*16+lk*4+r][q=qw+f*16+lrow]
            f32x4 s[2][4];
            __builtin_amdgcn_s_setprio(1);
            #pragma unroll
            for (int c = 0; c < 4; ++c) {
                if (c >= 2 && !fullc) continue;
                const bf16x8 k0 = ld_bf8(&Ks[c*16 + lrow][((0 + lk) ^ swz) * 8]);
                const bf16x8 k1 = ld_bf8(&Ks[c*16 + lrow][((4 + lk) ^ swz) * 8]);
                #pragma unroll
                for (int f = 0; f < 2; ++f) {
                    f32x4 z = {};
                    z = __builtin_amdgcn_mfma_f32_16x16x32_bf16(k0, qf[f][0], z, 0, 0, 0);
                    z = __builtin_amdgcn_mfma_f32_16x16x32_bf16(k1, qf[f][1], z, 0, 0, 0);
                    s[f][c] = z;
                }
            }
            __builtin_amdgcn_s_setprio(0);

            #pragma unroll
            for (int f = 0; f < 2; ++f) {
                const int q = qw + f*16 + lrow;
                float mx = -3e38f;
                #pragma unroll
                for (int c = 0; c < 4; ++c) {
                    if (c >= 2 && !fullc) continue;
                    #pragma unroll
                    for (int r = 0; r < 4; ++r) {
                        float v = s[f][c][r];                    // raw (scale folded into exp)
                        if (needmask && (kv0 + c*16 + lk*4 + r > q)) v = -1e30f;
                        s[f][c][r] = v;
                        mx = fmaxf(mx, v);
                    }
                }
                mx = fmaxf(mx, __shfl_xor(mx, 16));
                mx = fmaxf(mx, __shfl_xor(mx, 32));
                if (__any(mx > m[f] + 64.f)) {                   // defer-max, THR=8 scaled
                    const float mn = fmaxf(m[f], mx);
                    const float al = __expf((m[f] - mn) * 0.125f);
                    lsum[f] *= al;
                    m[f] = mn;
                    #pragma unroll
                    for (int c = 0; c < 4; ++c)
                    #pragma unroll
                    for (int r = 0; r < 4; ++r) o[f][c][r] *= al;
                }
                float ps = 0.f;
                #pragma unroll
                for (int c = 0; c < 4; ++c) {
                    if (c >= 2 && !fullc) continue;
                    #pragma unroll
                    for (int r = 0; r < 4; ++r) {
                        const float p = __expf((s[f][c][r] - m[f]) * 0.125f);
                        s[f][c][r] = p;
                        ps += p;
                    }
                }
                ps += __shfl_xor(ps, 16);
                ps += __shfl_xor(ps, 32);
                lsum[f] += ps;
            }

            // PV from registers: o[f][chd] += sum_c V^T-chunk x P^T-chunk (K=16)
            __builtin_amdgcn_s_setprio(1);
            #pragma unroll
            for (int c = 0; c < 4; ++c) {
                if (c >= 2 && !fullc) continue;
                union { bf16x4 v; f32x2 f; } p0, p1;
                #pragma unroll
                for (int r = 0; r < 4; ++r) {
                    p0.v[r] = (__bf16)s[0][c][r];
                    p1.v[r] = (__bf16)s[1][c][r];
                }
                #pragma unroll
                for (int chd = 0; chd < 4; ++chd) {
                    const f32x2 va = *reinterpret_cast<const f32x2*>(
                        &Vs[chd*16 + lrow][(((c*2 + (lk >> 1)) ^ swz) << 3) + ((lk & 1) << 2)]);
                    mfma16(o[0][chd], va, p0.f);
                    mfma16(o[1][chd], va, p1.f);
                }
            }
            __builtin_amdgcn_s_setprio(0);
        }
        __syncthreads();
        cur ^= 1;
    }

    const int b = bh >> 4, h = bh & 15;
    #pragma unroll
    for (int f = 0; f < 2; ++f) {
        const float rl = 1.0f / lsum[f];
        #pragma unroll
        for (int chd = 0; chd < 4; ++chd) {
            u16 ov[4] = { f2bf(o[f][chd][0]*rl), f2bf(o[f][chd][1]*rl),
                          f2bf(o[f][chd][2]*rl), f2bf(o[f][chd][3]*rl) };
            *(ushort4*)(AO + ((size_t)(b*Tsz + qw + f*16 + lrow))*Dsz
                           + h*HDsz + chd*16 + lk*4) = *(ushort4*)ov;
        }
    }
}

extern "C" void kernel_launch(void* const* d_in, const int* in_sizes, int n_in,
                              void* d_out, int out_size, void* d_ws, size_t ws_size,
                              hipStream_t stream)
{
    (void)in_sizes; (void)n_in; (void)out_size; (void)ws_size;

    const float* x      = (const float*)d_in[0];
    const float* qkv_w  = (const float*)d_in[1];
    const float* qkv_b  = (const float*)d_in[2];
    const float* proj_w = (const float*)d_in[3];
    const float* proj_b = (const float*)d_in[4];
    float* out = (float*)d_out;

    char* ws = (char*)d_ws;
    const size_t SZ = (size_t)Bsz * Hsz * Tsz * HDsz * sizeof(u16);  // 16 MB
    u16* R0 = (u16*)(ws);
    u16* Qb = (u16*)(ws + SZ);
    u16* Kb = (u16*)(ws + 2*SZ);
    u16* Vt = (u16*)(ws + 3*SZ);
    u16* WQKVT = R0;          // dead after QKV GEMM
    u16* AO    = R0;          // reuses WQKVT region
    u16* WPT   = Qb;          // reuses Q region after attention

    const int M = Bsz * Tsz;  // 8192

    transpose_w<<<dim3(3*Dsz/64, Dsz/64), 256, 0, stream>>>(qkv_w, WQKVT, Dsz, 3*Dsz);
    gemm128<1, 0><<<dim3(3*Dsz/128, M/128), 256, 0, stream>>>(
        x, WQKVT, qkv_b, nullptr, Qb, Kb, Vt, M, 3*Dsz, Dsz);
    attn3<<<dim3(Tsz/128, Bsz*Hsz), 256, 0, stream>>>(Qb, Kb, Vt, AO);
    transpose_w<<<dim3(Dsz/64, Dsz/64), 256, 0, stream>>>(proj_w, WPT, Dsz, Dsz);
    gemm128<0, 1><<<dim3(Dsz/128, M/128), 256, 0, stream>>>(
        AO, WPT, proj_b, out, nullptr, nullptr, nullptr, M, Dsz, Dsz);
}

// Round 4
// 244.601 us; speedup vs baseline: 3.1236x; 1.0130x over previous
//
#include <hip/hip_runtime.h>
#include <hip/hip_bf16.h>

// B=4, T=2048, D=1024, H=16, HD=64
#define Bsz 4
#define Tsz 2048
#define Dsz 1024
#define Hsz 16
#define HDsz 64

typedef __attribute__((ext_vector_type(8))) __bf16 bf16x8;
typedef __attribute__((ext_vector_type(4))) __bf16 bf16x4;
typedef __attribute__((ext_vector_type(4))) float f32x4;
typedef __attribute__((ext_vector_type(2))) float f32x2;
typedef unsigned short u16;
typedef unsigned int u32;

#define DEVI static __device__ __forceinline__

DEVI u16 f2bf(float f) {
    __bf16 h = (__bf16)f;
    union { __bf16 h; u16 u; } c; c.h = h; return c.u;
}
DEVI bf16x8 ld_bf8(const u16* p) { return *reinterpret_cast<const bf16x8*>(p); }

// async global->LDS, 16B per lane. lds dest is wave-uniform base + lane*16.
DEVI void gll16(const u16* g, u16* lds) {
    __builtin_amdgcn_global_load_lds(
        (const __attribute__((address_space(1))) u32*)g,
        (__attribute__((address_space(3))) u32*)lds, 16, 0, 0);
}

// K=16 MFMA: acc(16x16, f32) += A(16x16 bf16) * B(16x16 bf16).
DEVI void mfma16(f32x4& c, f32x2 a, f32x2 b) {
    asm("v_mfma_f32_16x16x16_bf16 %0, %1, %2, %0" : "+v"(c) : "v"(a), "v"(b));
}

// ---------------------------------------------------------------------------
// fp32 -> bf16 bulk convert (8 elems/thread, single pass)
// ---------------------------------------------------------------------------
__global__ __launch_bounds__(256)
void conv_bf16(const float* __restrict__ X, u16* __restrict__ Xb)
{
    const size_t i = ((size_t)blockIdx.x * 256 + threadIdx.x) * 8;
    const float4 a = *(const float4*)(X + i);
    const float4 b = *(const float4*)(X + i + 4);
    u16 h[8] = { f2bf(a.x), f2bf(a.y), f2bf(a.z), f2bf(a.w),
                 f2bf(b.x), f2bf(b.y), f2bf(b.z), f2bf(b.w) };
    *(uint4*)(Xb + i) = *(uint4*)h;
}

// ---------------------------------------------------------------------------
// Transpose+convert: W[K][N] fp32 -> WT[N][K] bf16. 64x64 tiles.
// ---------------------------------------------------------------------------
__global__ __launch_bounds__(256)
void transpose_w(const float* __restrict__ W, u16* __restrict__ WT, int K, int N)
{
    __shared__ float tile[64][65];
    const int n0 = blockIdx.x * 64, k0 = blockIdx.y * 64;
    const int t = threadIdx.x;
    #pragma unroll
    for (int i = 0; i < 4; ++i) {
        const int idx = i*256 + t;
        const int row = idx >> 4, c4 = (idx & 15) * 4;
        const float4 v = *(const float4*)(W + (size_t)(k0 + row)*N + n0 + c4);
        tile[row][c4+0] = v.x; tile[row][c4+1] = v.y;
        tile[row][c4+2] = v.z; tile[row][c4+3] = v.w;
    }
    __syncthreads();
    #pragma unroll
    for (int j = 0; j < 2; ++j) {
        const int idx = j*256 + t;
        const int nr = idx >> 3, kc = (idx & 7) * 8;
        u16 h[8];
        #pragma unroll
        for (int e = 0; e < 8; ++e) h[e] = f2bf(tile[kc + e][nr]);
        *(uint4*)(WT + (size_t)(n0 + nr)*K + k0 + kc) = *(uint4*)h;
    }
}

// ---------------------------------------------------------------------------
// 128x128 bf16 MFMA GEMM, BK=32, 4 waves, 4x4 frags/wave.
// Both operands bf16 [.,K] via global_load_lds; double-buffered LDS (2-phase):
// issue next tile's staging before current tile's ds_read+MFMA, one barrier
// per k-step. LDS XOR-swizzle (chunk ^= (row>>1)&3), pre-swizzled source.
// ---------------------------------------------------------------------------
template<int EPI>
__global__ __launch_bounds__(256, 4)
void gemm128(const u16* __restrict__ A, const u16* __restrict__ Bt,
             const float* __restrict__ bias, float* __restrict__ Cf,
             u16* __restrict__ Qo, u16* __restrict__ Ko, u16* __restrict__ Vo,
             int M, int N, int K)
{
    __shared__ u16 As[2][128][32];
    __shared__ u16 Bs[2][128][32];
    const int tN = blockIdx.x, tM = blockIdx.y;
    const int t = threadIdx.x, l = t & 63, w = t >> 6;
    const int wm = w >> 1, wn = w & 1;
    const int lrow = l & 15, lk = l >> 4;

    f32x4 acc[4][4] = {};

    const u16* Ag = A  + (size_t)tM * 128 * K;
    const u16* Bg = Bt + (size_t)tN * 128 * K;

    // per-thread staging coords (2 rounds x 256 threads covering 128x32)
    int srow[2], sch[2];
    #pragma unroll
    for (int r = 0; r < 2; ++r) {
        const int c = r*256 + t;
        srow[r] = c >> 2;
        sch[r]  = (c & 3) ^ ((srow[r] >> 1) & 3);
    }
    const size_t ldso = (size_t)(t & 192) * 8;

    #pragma unroll
    for (int r = 0; r < 2; ++r) {
        gll16(Ag + (size_t)srow[r]*K + sch[r]*8, &As[0][0][0] + (size_t)r*2048 + ldso);
        gll16(Bg + (size_t)srow[r]*K + sch[r]*8, &Bs[0][0][0] + (size_t)r*2048 + ldso);
    }
    __syncthreads();

    int cur = 0;
    for (int ks = 0; ks < K; ks += 32) {
        if (ks + 32 < K) {
            const int nb = cur ^ 1;
            #pragma unroll
            for (int r = 0; r < 2; ++r) {
                gll16(Ag + (size_t)srow[r]*K + ks + 32 + sch[r]*8,
                      &As[nb][0][0] + (size_t)r*2048 + ldso);
                gll16(Bg + (size_t)srow[r]*K + ks + 32 + sch[r]*8,
                      &Bs[nb][0][0] + (size_t)r*2048 + ldso);
            }
        }
        bf16x8 a[4], bb[4];
        #pragma unroll
        for (int i = 0; i < 4; ++i) {
            const int ar = wm*64 + i*16 + lrow;
            a[i] = ld_bf8(&As[cur][ar][(lk ^ ((ar >> 1) & 3)) * 8]);
        }
        #pragma unroll
        for (int j = 0; j < 4; ++j) {
            const int br = wn*64 + j*16 + lrow;
            bb[j] = ld_bf8(&Bs[cur][br][(lk ^ ((br >> 1) & 3)) * 8]);
        }
        __builtin_amdgcn_s_setprio(1);
        #pragma unroll
        for (int i = 0; i < 4; ++i)
        #pragma unroll
        for (int j = 0; j < 4; ++j)
            acc[i][j] = __builtin_amdgcn_mfma_f32_16x16x32_bf16(a[i], bb[j], acc[i][j], 0, 0, 0);
        __builtin_amdgcn_s_setprio(0);
        __syncthreads();          // drains prefetch vmcnt + lgkm; swap safe
        cur ^= 1;
    }

    #pragma unroll
    for (int i = 0; i < 4; ++i)
    #pragma unroll
    for (int j = 0; j < 4; ++j)
    #pragma unroll
    for (int r = 0; r < 4; ++r) {
        const int row = tM*128 + wm*64 + i*16 + lk*4 + r;
        const int col = tN*128 + wn*64 + j*16 + lrow;
        const float v = acc[i][j][r] + bias[col];
        if (EPI == 0) {
            Cf[(size_t)row * N + col] = v;
        } else {
            const int which = col >> 10;
            const int h  = (col & 1023) >> 6;
            const int hd = col & 63;
            const int b  = row >> 11;
            const int tt = row & 2047;
            const int bh = b * Hsz + h;
            const u16 bv = f2bf(v);
            if (which == 0)      Qo[((size_t)bh * Tsz + tt) * HDsz + hd] = bv;
            else if (which == 1) Ko[((size_t)bh * Tsz + tt) * HDsz + hd] = bv;
            else                 Vo[((size_t)bh * HDsz + hd) * Tsz + tt] = bv;
        }
    }
}

// ---------------------------------------------------------------------------
// Flash attention v3 (causal). 4 waves x 32 q-rows; KVBLK=64, double-buffered.
// LDS = 32 KB (no P buffer): swapped QK^T leaves P^T in the exact B-fragment
// layout of v_mfma_f32_16x16x16_bf16, so PV consumes P from registers.
// Defer-max (THR=8 scaled = 64 raw). Balanced heavy/light qt pairing.
// ---------------------------------------------------------------------------
__global__ __launch_bounds__(256, 4)
void attn3(const u16* __restrict__ Q, const u16* __restrict__ K,
           const u16* __restrict__ Vt, u16* __restrict__ AO)
{
    __shared__ u16 KV[2][2][64][64];   // [buf][K/V][row][col], 32 KB

    const int bh = blockIdx.y;
    const int xx = blockIdx.x;
    const int qt = (xx & 1) ? (xx >> 1) : ((int)gridDim.x - 1 - (xx >> 1));
    const int t = threadIdx.x, w = t >> 6, l = t & 63;
    const int lrow = l & 15, lk = l >> 4;
    const int qw = qt*128 + w*32;
    const int qwmax = qw + 31;
    const int swz = lrow & 7;

    const u16* Qh = Q  + (size_t)bh * Tsz * HDsz;
    const u16* Kh = K  + (size_t)bh * Tsz * HDsz;
    const u16* Vh = Vt + (size_t)bh * HDsz * Tsz;

    bf16x8 qf[2][2];
    #pragma unroll
    for (int f = 0; f < 2; ++f)
    #pragma unroll
    for (int kh = 0; kh < 2; ++kh)
        qf[f][kh] = ld_bf8(&Qh[(size_t)(qw + f*16 + lrow)*HDsz + kh*32 + lk*8]);

    f32x4 o[2][4] = {};
    float m[2] = {-3e38f, -3e38f}, lsum[2] = {0.f, 0.f};

    const int ntile = 2*qt + 2;
    int cur = 0;

    #pragma unroll
    for (int rr = 0; rr < 2; ++rr) {
        const int c = rr*256 + t;
        const int row = c >> 3, gc = (c & 7) ^ (row & 7);
        gll16(Kh + (size_t)row*HDsz + gc*8,
              &KV[0][0][0][0] + (size_t)(rr*256 + (t & 192))*8);
        gll16(Vh + (size_t)row*Tsz + gc*8,
              &KV[0][1][0][0] + (size_t)(rr*256 + (t & 192))*8);
    }
    __syncthreads();

    for (int tk = 0; tk < ntile; ++tk) {
        if (tk + 1 < ntile) {
            const int nkv = (tk + 1) * 64;
            #pragma unroll
            for (int rr = 0; rr < 2; ++rr) {
                const int c = rr*256 + t;
                const int row = c >> 3, gc = (c & 7) ^ (row & 7);
                gll16(Kh + (size_t)(nkv + row)*HDsz + gc*8,
                      &KV[cur^1][0][0][0] + (size_t)(rr*256 + (t & 192))*8);
                gll16(Vh + (size_t)row*Tsz + nkv + gc*8,
                      &KV[cur^1][1][0][0] + (size_t)(rr*256 + (t & 192))*8);
            }
        }
        const int kv0 = tk * 64;
        if (kv0 <= qwmax) {
            const u16 (*Ks)[64] = KV[cur][0];
            const u16 (*Vs)[64] = KV[cur][1];
            const bool fullc    = (kv0 + 63 <= qwmax);
            const bool needmask = (kv0 + 63 > qw);

            f32x4 s[2][4];
            __builtin_amdgcn_s_setprio(1);
            #pragma unroll
            for (int c = 0; c < 4; ++c) {
                if (c >= 2 && !fullc) continue;
                const bf16x8 k0 = ld_bf8(&Ks[c*16 + lrow][((0 + lk) ^ swz) * 8]);
                const bf16x8 k1 = ld_bf8(&Ks[c*16 + lrow][((4 + lk) ^ swz) * 8]);
                #pragma unroll
                for (int f = 0; f < 2; ++f) {
                    f32x4 z = {};
                    z = __builtin_amdgcn_mfma_f32_16x16x32_bf16(k0, qf[f][0], z, 0, 0, 0);
                    z = __builtin_amdgcn_mfma_f32_16x16x32_bf16(k1, qf[f][1], z, 0, 0, 0);
                    s[f][c] = z;
                }
            }
            __builtin_amdgcn_s_setprio(0);

            #pragma unroll
            for (int f = 0; f < 2; ++f) {
                const int q = qw + f*16 + lrow;
                float mx = -3e38f;
                #pragma unroll
                for (int c = 0; c < 4; ++c) {
                    if (c >= 2 && !fullc) continue;
                    #pragma unroll
                    for (int r = 0; r < 4; ++r) {
                        float v = s[f][c][r];
                        if (needmask && (kv0 + c*16 + lk*4 + r > q)) v = -1e30f;
                        s[f][c][r] = v;
                        mx = fmaxf(mx, v);
                    }
                }
                mx = fmaxf(mx, __shfl_xor(mx, 16));
                mx = fmaxf(mx, __shfl_xor(mx, 32));
                if (__any(mx > m[f] + 64.f)) {
                    const float mn = fmaxf(m[f], mx);
                    const float al = __expf((m[f] - mn) * 0.125f);
                    lsum[f] *= al;
                    m[f] = mn;
                    #pragma unroll
                    for (int c = 0; c < 4; ++c)
                    #pragma unroll
                    for (int r = 0; r < 4; ++r) o[f][c][r] *= al;
                }
                float ps = 0.f;
                #pragma unroll
                for (int c = 0; c < 4; ++c) {
                    if (c >= 2 && !fullc) continue;
                    #pragma unroll
                    for (int r = 0; r < 4; ++r) {
                        const float p = __expf((s[f][c][r] - m[f]) * 0.125f);
                        s[f][c][r] = p;
                        ps += p;
                    }
                }
                ps += __shfl_xor(ps, 16);
                ps += __shfl_xor(ps, 32);
                lsum[f] += ps;
            }

            __builtin_amdgcn_s_setprio(1);
            #pragma unroll
            for (int c = 0; c < 4; ++c) {
                if (c >= 2 && !fullc) continue;
                union { bf16x4 v; f32x2 f; } p0, p1;
                #pragma unroll
                for (int r = 0; r < 4; ++r) {
                    p0.v[r] = (__bf16)s[0][c][r];
                    p1.v[r] = (__bf16)s[1][c][r];
                }
                #pragma unroll
                for (int chd = 0; chd < 4; ++chd) {
                    const f32x2 va = *reinterpret_cast<const f32x2*>(
                        &Vs[chd*16 + lrow][(((c*2 + (lk >> 1)) ^ swz) << 3) + ((lk & 1) << 2)]);
                    mfma16(o[0][chd], va, p0.f);
                    mfma16(o[1][chd], va, p1.f);
                }
            }
            __builtin_amdgcn_s_setprio(0);
        }
        __syncthreads();
        cur ^= 1;
    }

    const int b = bh >> 4, h = bh & 15;
    #pragma unroll
    for (int f = 0; f < 2; ++f) {
        const float rl = 1.0f / lsum[f];
        #pragma unroll
        for (int chd = 0; chd < 4; ++chd) {
            u16 ov[4] = { f2bf(o[f][chd][0]*rl), f2bf(o[f][chd][1]*rl),
                          f2bf(o[f][chd][2]*rl), f2bf(o[f][chd][3]*rl) };
            *(ushort4*)(AO + ((size_t)(b*Tsz + qw + f*16 + lrow))*Dsz
                           + h*HDsz + chd*16 + lk*4) = *(ushort4*)ov;
        }
    }
}

extern "C" void kernel_launch(void* const* d_in, const int* in_sizes, int n_in,
                              void* d_out, int out_size, void* d_ws, size_t ws_size,
                              hipStream_t stream)
{
    (void)in_sizes; (void)n_in; (void)out_size; (void)ws_size;

    const float* x      = (const float*)d_in[0];
    const float* qkv_w  = (const float*)d_in[1];
    const float* qkv_b  = (const float*)d_in[2];
    const float* proj_w = (const float*)d_in[3];
    const float* proj_b = (const float*)d_in[4];
    float* out = (float*)d_out;

    char* ws = (char*)d_ws;
    const size_t SZ = (size_t)Bsz * Hsz * Tsz * HDsz * sizeof(u16);  // 16 MB
    u16* R0 = (u16*)(ws);
    u16* Qb = (u16*)(ws + SZ);
    u16* Kb = (u16*)(ws + 2*SZ);
    u16* Vt = (u16*)(ws + 3*SZ);
    u16* WQKVT = R0;          // dead after QKV GEMM
    u16* AO    = R0;          // reuses WQKVT region
    u16* WPT   = Qb;          // reuses Q region after attention

    // x as bf16, staged in d_out's first 16.8 MB (out is 33.5 MB fp32,
    // fully overwritten by the proj GEMM at the end -> safe scratch).
    u16* Xb = (u16*)d_out;

    const int M = Bsz * Tsz;  // 8192

    conv_bf16<<<(M*Dsz)/(256*8), 256, 0, stream>>>(x, Xb);
    transpose_w<<<dim3(3*Dsz/64, Dsz/64), 256, 0, stream>>>(qkv_w, WQKVT, Dsz, 3*Dsz);
    gemm128<1><<<dim3(3*Dsz/128, M/128), 256, 0, stream>>>(
        Xb, WQKVT, qkv_b, nullptr, Qb, Kb, Vt, M, 3*Dsz, Dsz);
    attn3<<<dim3(Tsz/128, Bsz*Hsz), 256, 0, stream>>>(Qb, Kb, Vt, AO);
    transpose_w<<<dim3(Dsz/64, Dsz/64), 256, 0, stream>>>(proj_w, WPT, Dsz, Dsz);
    gemm128<0><<<dim3(Dsz/128, M/128), 256, 0, stream>>>(
        AO, WPT, proj_b, out, nullptr, nullptr, nullptr, M, Dsz, Dsz);
}

// Round 5
// 215.083 us; speedup vs baseline: 3.5523x; 1.1372x over previous
//
#include <hip/hip_runtime.h>
#include <hip/hip_bf16.h>

// B=4, T=2048, D=1024, H=16, HD=64
#define Bsz 4
#define Tsz 2048
#define Dsz 1024
#define Hsz 16
#define HDsz 64

typedef __attribute__((ext_vector_type(8))) __bf16 bf16x8;
typedef __attribute__((ext_vector_type(4))) __bf16 bf16x4;
typedef __attribute__((ext_vector_type(4))) float f32x4;
typedef __attribute__((ext_vector_type(2))) float f32x2;
typedef unsigned short u16;
typedef unsigned int u32;

#define DEVI static __device__ __forceinline__

DEVI u16 f2bf(float f) {
    __bf16 h = (__bf16)f;
    union { __bf16 h; u16 u; } c; c.h = h; return c.u;
}
DEVI bf16x8 ld_bf8(const u16* p) { return *reinterpret_cast<const bf16x8*>(p); }

// async global->LDS, 16B per lane. lds dest is wave-uniform base + lane*16.
DEVI void gll16(const u16* g, u16* lds) {
    __builtin_amdgcn_global_load_lds(
        (const __attribute__((address_space(1))) u32*)g,
        (__attribute__((address_space(3))) u32*)lds, 16, 0, 0);
}

// K=16 MFMA: acc(16x16, f32) += A(16x16 bf16) * B(16x16 bf16).
DEVI void mfma16(f32x4& c, f32x2 a, f32x2 b) {
    asm("v_mfma_f32_16x16x16_bf16 %0, %1, %2, %0" : "+v"(c) : "v"(a), "v"(b));
}

// ---------------------------------------------------------------------------
// fp32 -> bf16 bulk convert (8 elems/thread, single pass)
// ---------------------------------------------------------------------------
__global__ __launch_bounds__(256)
void conv_bf16(const float* __restrict__ X, u16* __restrict__ Xb)
{
    const size_t i = ((size_t)blockIdx.x * 256 + threadIdx.x) * 8;
    const float4 a = *(const float4*)(X + i);
    const float4 b = *(const float4*)(X + i + 4);
    u16 h[8] = { f2bf(a.x), f2bf(a.y), f2bf(a.z), f2bf(a.w),
                 f2bf(b.x), f2bf(b.y), f2bf(b.z), f2bf(b.w) };
    *(uint4*)(Xb + i) = *(uint4*)h;
}

// ---------------------------------------------------------------------------
// Transpose+convert: W[K][N] fp32 -> WT[N][K] bf16. 64x64 tiles.
// ---------------------------------------------------------------------------
__global__ __launch_bounds__(256)
void transpose_w(const float* __restrict__ W, u16* __restrict__ WT, int K, int N)
{
    __shared__ float tile[64][65];
    const int n0 = blockIdx.x * 64, k0 = blockIdx.y * 64;
    const int t = threadIdx.x;
    #pragma unroll
    for (int i = 0; i < 4; ++i) {
        const int idx = i*256 + t;
        const int row = idx >> 4, c4 = (idx & 15) * 4;
        const float4 v = *(const float4*)(W + (size_t)(k0 + row)*N + n0 + c4);
        tile[row][c4+0] = v.x; tile[row][c4+1] = v.y;
        tile[row][c4+2] = v.z; tile[row][c4+3] = v.w;
    }
    __syncthreads();
    #pragma unroll
    for (int j = 0; j < 2; ++j) {
        const int idx = j*256 + t;
        const int nr = idx >> 3, kc = (idx & 7) * 8;
        u16 h[8];
        #pragma unroll
        for (int e = 0; e < 8; ++e) h[e] = f2bf(tile[kc + e][nr]);
        *(uint4*)(WT + (size_t)(n0 + nr)*K + k0 + kc) = *(uint4*)h;
    }
}

// ---------------------------------------------------------------------------
// 128x128 bf16 MFMA GEMM, BK=32, 4 waves, 4x4 frags/wave.
// Both operands bf16 [.,K] via global_load_lds; double-buffered LDS (2-phase).
// LDS XOR-swizzle (chunk ^= (row>>1)&3), pre-swizzled source.
// ---------------------------------------------------------------------------
template<int EPI>
__global__ __launch_bounds__(256, 4)
void gemm128(const u16* __restrict__ A, const u16* __restrict__ Bt,
             const float* __restrict__ bias, float* __restrict__ Cf,
             u16* __restrict__ Qo, u16* __restrict__ Ko, u16* __restrict__ Vo,
             int M, int N, int K)
{
    __shared__ u16 As[2][128][32];
    __shared__ u16 Bs[2][128][32];
    const int tN = blockIdx.x, tM = blockIdx.y;
    const int t = threadIdx.x, l = t & 63, w = t >> 6;
    const int wm = w >> 1, wn = w & 1;
    const int lrow = l & 15, lk = l >> 4;

    f32x4 acc[4][4] = {};

    const u16* Ag = A  + (size_t)tM * 128 * K;
    const u16* Bg = Bt + (size_t)tN * 128 * K;

    int srow[2], sch[2];
    #pragma unroll
    for (int r = 0; r < 2; ++r) {
        const int c = r*256 + t;
        srow[r] = c >> 2;
        sch[r]  = (c & 3) ^ ((srow[r] >> 1) & 3);
    }
    const size_t ldso = (size_t)(t & 192) * 8;

    #pragma unroll
    for (int r = 0; r < 2; ++r) {
        gll16(Ag + (size_t)srow[r]*K + sch[r]*8, &As[0][0][0] + (size_t)r*2048 + ldso);
        gll16(Bg + (size_t)srow[r]*K + sch[r]*8, &Bs[0][0][0] + (size_t)r*2048 + ldso);
    }
    __syncthreads();

    int cur = 0;
    for (int ks = 0; ks < K; ks += 32) {
        if (ks + 32 < K) {
            const int nb = cur ^ 1;
            #pragma unroll
            for (int r = 0; r < 2; ++r) {
                gll16(Ag + (size_t)srow[r]*K + ks + 32 + sch[r]*8,
                      &As[nb][0][0] + (size_t)r*2048 + ldso);
                gll16(Bg + (size_t)srow[r]*K + ks + 32 + sch[r]*8,
                      &Bs[nb][0][0] + (size_t)r*2048 + ldso);
            }
        }
        bf16x8 a[4], bb[4];
        #pragma unroll
        for (int i = 0; i < 4; ++i) {
            const int ar = wm*64 + i*16 + lrow;
            a[i] = ld_bf8(&As[cur][ar][(lk ^ ((ar >> 1) & 3)) * 8]);
        }
        #pragma unroll
        for (int j = 0; j < 4; ++j) {
            const int br = wn*64 + j*16 + lrow;
            bb[j] = ld_bf8(&Bs[cur][br][(lk ^ ((br >> 1) & 3)) * 8]);
        }
        __builtin_amdgcn_s_setprio(1);
        #pragma unroll
        for (int i = 0; i < 4; ++i)
        #pragma unroll
        for (int j = 0; j < 4; ++j)
            acc[i][j] = __builtin_amdgcn_mfma_f32_16x16x32_bf16(a[i], bb[j], acc[i][j], 0, 0, 0);
        __builtin_amdgcn_s_setprio(0);
        __syncthreads();
        cur ^= 1;
    }

    #pragma unroll
    for (int i = 0; i < 4; ++i)
    #pragma unroll
    for (int j = 0; j < 4; ++j)
    #pragma unroll
    for (int r = 0; r < 4; ++r) {
        const int row = tM*128 + wm*64 + i*16 + lk*4 + r;
        const int col = tN*128 + wn*64 + j*16 + lrow;
        const float v = acc[i][j][r] + bias[col];
        if (EPI == 0) {
            Cf[(size_t)row * N + col] = v;
        } else {
            const int which = col >> 10;
            const int h  = (col & 1023) >> 6;
            const int hd = col & 63;
            const int b  = row >> 11;
            const int tt = row & 2047;
            const int bh = b * Hsz + h;
            const u16 bv = f2bf(v);
            if (which == 0)      Qo[((size_t)bh * Tsz + tt) * HDsz + hd] = bv;
            else if (which == 1) Ko[((size_t)bh * Tsz + tt) * HDsz + hd] = bv;
            else                 Vo[((size_t)bh * HDsz + hd) * Tsz + tt] = bv;
        }
    }
}

// ---------------------------------------------------------------------------
// Flash attention v4 (causal). 4 waves x 32 q-rows; KVBLK=64, double-buffered.
// P stays in registers (16x16x16 PV). Defer-max. NEW: per-CU balanced qt
// swizzle — at dispatch stride 256, a CU's 4 blocks get 4 consecutive idx
// values; perm[idx] makes any 4 consecutive idx sum to ~30 with 2 heavy +
// 2 light tiles, fixing the all-heavy/all-light CU pathology.
// Softmax uses tree max (v_max3) + 4 parallel partial sums + fmaf exp arg.
// ---------------------------------------------------------------------------
__global__ __launch_bounds__(256, 4)
void attn3(const u16* __restrict__ Q, const u16* __restrict__ K,
           const u16* __restrict__ Vt, u16* __restrict__ AO)
{
    __shared__ u16 KV[2][2][64][64];   // [buf][K/V][row][col], 32 KB

    const int y = blockIdx.y;                       // bh
    const int x = blockIdx.x;                       // 0..15
    const int idx = (x + (y >> 4)) & 15;
    const int qt = (idx & 1) ? (idx >> 1) : (15 - (idx >> 1));
    const int bh = y;
    const int t = threadIdx.x, w = t >> 6, l = t & 63;
    const int lrow = l & 15, lk = l >> 4;
    const int qw = qt*128 + w*32;
    const int qwmax = qw + 31;
    const int swz = lrow & 7;

    const u16* Qh = Q  + (size_t)bh * Tsz * HDsz;
    const u16* Kh = K  + (size_t)bh * Tsz * HDsz;
    const u16* Vh = Vt + (size_t)bh * HDsz * Tsz;

    bf16x8 qf[2][2];
    #pragma unroll
    for (int f = 0; f < 2; ++f)
    #pragma unroll
    for (int kh = 0; kh < 2; ++kh)
        qf[f][kh] = ld_bf8(&Qh[(size_t)(qw + f*16 + lrow)*HDsz + kh*32 + lk*8]);

    f32x4 o[2][4] = {};
    float m[2] = {-3e38f, -3e38f}, lsum[2] = {0.f, 0.f};

    const int ntile = 2*qt + 2;
    int cur = 0;

    #pragma unroll
    for (int rr = 0; rr < 2; ++rr) {
        const int c = rr*256 + t;
        const int row = c >> 3, gc = (c & 7) ^ (row & 7);
        gll16(Kh + (size_t)row*HDsz + gc*8,
              &KV[0][0][0][0] + (size_t)(rr*256 + (t & 192))*8);
        gll16(Vh + (size_t)row*Tsz + gc*8,
              &KV[0][1][0][0] + (size_t)(rr*256 + (t & 192))*8);
    }
    __syncthreads();

    for (int tk = 0; tk < ntile; ++tk) {
        if (tk + 1 < ntile) {
            const int nkv = (tk + 1) * 64;
            #pragma unroll
            for (int rr = 0; rr < 2; ++rr) {
                const int c = rr*256 + t;
                const int row = c >> 3, gc = (c & 7) ^ (row & 7);
                gll16(Kh + (size_t)(nkv + row)*HDsz + gc*8,
                      &KV[cur^1][0][0][0] + (size_t)(rr*256 + (t & 192))*8);
                gll16(Vh + (size_t)row*Tsz + nkv + gc*8,
                      &KV[cur^1][1][0][0] + (size_t)(rr*256 + (t & 192))*8);
            }
        }
        const int kv0 = tk * 64;
        if (kv0 <= qwmax) {
            const u16 (*Ks)[64] = KV[cur][0];
            const u16 (*Vs)[64] = KV[cur][1];
            const bool fullc    = (kv0 + 63 <= qwmax);
            const bool needmask = (kv0 + 63 > qw);

            f32x4 s[2][4];
            __builtin_amdgcn_s_setprio(1);
            #pragma unroll
            for (int c = 0; c < 4; ++c) {
                if (c >= 2 && !fullc) continue;
                const bf16x8 k0 = ld_bf8(&Ks[c*16 + lrow][((0 + lk) ^ swz) * 8]);
                const bf16x8 k1 = ld_bf8(&Ks[c*16 + lrow][((4 + lk) ^ swz) * 8]);
                #pragma unroll
                for (int f = 0; f < 2; ++f) {
                    f32x4 z = {};
                    z = __builtin_amdgcn_mfma_f32_16x16x32_bf16(k0, qf[f][0], z, 0, 0, 0);
                    z = __builtin_amdgcn_mfma_f32_16x16x32_bf16(k1, qf[f][1], z, 0, 0, 0);
                    s[f][c] = z;
                }
            }
            __builtin_amdgcn_s_setprio(0);

            #pragma unroll
            for (int f = 0; f < 2; ++f) {
                const int q = qw + f*16 + lrow;
                if (needmask) {
                    #pragma unroll
                    for (int c = 0; c < 4; ++c) {
                        if (c >= 2 && !fullc) continue;
                        const int base = kv0 + c*16 + lk*4;
                        #pragma unroll
                        for (int r = 0; r < 4; ++r)
                            if (base + r > q) s[f][c][r] = -1e30f;
                    }
                }
                // tree max (depth ~5, fuses to v_max3)
                f32x4 t01;
                #pragma unroll
                for (int r = 0; r < 4; ++r) {
                    t01[r] = fmaxf(s[f][0][r], s[f][1][r]);
                    if (fullc) t01[r] = fmaxf(t01[r], fmaxf(s[f][2][r], s[f][3][r]));
                }
                float mx = fmaxf(fmaxf(t01[0], t01[1]), fmaxf(t01[2], t01[3]));
                mx = fmaxf(mx, __shfl_xor(mx, 16));
                mx = fmaxf(mx, __shfl_xor(mx, 32));
                if (__any(mx > m[f] + 64.f)) {          // defer-max (THR=8 scaled)
                    const float mn = fmaxf(m[f], mx);
                    const float al = __expf((m[f] - mn) * 0.125f);
                    lsum[f] *= al;
                    m[f] = mn;
                    #pragma unroll
                    for (int c = 0; c < 4; ++c)
                    #pragma unroll
                    for (int r = 0; r < 4; ++r) o[f][c][r] *= al;
                }
                const float nm8 = -m[f] * 0.125f;
                f32x4 ps4 = {};
                #pragma unroll
                for (int c = 0; c < 4; ++c) {
                    if (c >= 2 && !fullc) continue;
                    #pragma unroll
                    for (int r = 0; r < 4; ++r) {
                        const float p = __expf(fmaf(s[f][c][r], 0.125f, nm8));
                        s[f][c][r] = p;
                        ps4[r] += p;
                    }
                }
                float ps = (ps4[0] + ps4[1]) + (ps4[2] + ps4[3]);
                ps += __shfl_xor(ps, 16);
                ps += __shfl_xor(ps, 32);
                lsum[f] += ps;
            }

            __builtin_amdgcn_s_setprio(1);
            #pragma unroll
            for (int c = 0; c < 4; ++c) {
                if (c >= 2 && !fullc) continue;
                union { bf16x4 v; f32x2 f; } p0, p1;
                #pragma unroll
                for (int r = 0; r < 4; ++r) {
                    p0.v[r] = (__bf16)s[0][c][r];
                    p1.v[r] = (__bf16)s[1][c][r];
                }
                #pragma unroll
                for (int chd = 0; chd < 4; ++chd) {
                    const f32x2 va = *reinterpret_cast<const f32x2*>(
                        &Vs[chd*16 + lrow][(((c*2 + (lk >> 1)) ^ swz) << 3) + ((lk & 1) << 2)]);
                    mfma16(o[0][chd], va, p0.f);
                    mfma16(o[1][chd], va, p1.f);
                }
            }
            __builtin_amdgcn_s_setprio(0);
        }
        __syncthreads();
        cur ^= 1;
    }

    const int b = bh >> 4, h = bh & 15;
    #pragma unroll
    for (int f = 0; f < 2; ++f) {
        const float rl = 1.0f / lsum[f];
        #pragma unroll
        for (int chd = 0; chd < 4; ++chd) {
            u16 ov[4] = { f2bf(o[f][chd][0]*rl), f2bf(o[f][chd][1]*rl),
                          f2bf(o[f][chd][2]*rl), f2bf(o[f][chd][3]*rl) };
            *(ushort4*)(AO + ((size_t)(b*Tsz + qw + f*16 + lrow))*Dsz
                           + h*HDsz + chd*16 + lk*4) = *(ushort4*)ov;
        }
    }
}

extern "C" void kernel_launch(void* const* d_in, const int* in_sizes, int n_in,
                              void* d_out, int out_size, void* d_ws, size_t ws_size,
                              hipStream_t stream)
{
    (void)in_sizes; (void)n_in; (void)out_size; (void)ws_size;

    const float* x      = (const float*)d_in[0];
    const float* qkv_w  = (const float*)d_in[1];
    const float* qkv_b  = (const float*)d_in[2];
    const float* proj_w = (const float*)d_in[3];
    const float* proj_b = (const float*)d_in[4];
    float* out = (float*)d_out;

    char* ws = (char*)d_ws;
    const size_t SZ = (size_t)Bsz * Hsz * Tsz * HDsz * sizeof(u16);  // 16 MB
    u16* R0 = (u16*)(ws);
    u16* Qb = (u16*)(ws + SZ);
    u16* Kb = (u16*)(ws + 2*SZ);
    u16* Vt = (u16*)(ws + 3*SZ);
    u16* WQKVT = R0;          // dead after QKV GEMM
    u16* AO    = R0;          // reuses WQKVT region
    u16* WPT   = Qb;          // reuses Q region after attention

    // x as bf16, staged in d_out's first 16.8 MB (out is 33.5 MB fp32,
    // fully overwritten by the proj GEMM at the end -> safe scratch).
    u16* Xb = (u16*)d_out;

    const int M = Bsz * Tsz;  // 8192

    conv_bf16<<<(M*Dsz)/(256*8), 256, 0, stream>>>(x, Xb);
    transpose_w<<<dim3(3*Dsz/64, Dsz/64), 256, 0, stream>>>(qkv_w, WQKVT, Dsz, 3*Dsz);
    gemm128<1><<<dim3(3*Dsz/128, M/128), 256, 0, stream>>>(
        Xb, WQKVT, qkv_b, nullptr, Qb, Kb, Vt, M, 3*Dsz, Dsz);
    attn3<<<dim3(Tsz/128, Bsz*Hsz), 256, 0, stream>>>(Qb, Kb, Vt, AO);
    transpose_w<<<dim3(Dsz/64, Dsz/64), 256, 0, stream>>>(proj_w, WPT, Dsz, Dsz);
    gemm128<0><<<dim3(Dsz/128, M/128), 256, 0, stream>>>(
        AO, WPT, proj_b, out, nullptr, nullptr, nullptr, M, Dsz, Dsz);
}

// Round 6
// 201.551 us; speedup vs baseline: 3.7908x; 1.0671x over previous
//
#include <hip/hip_runtime.h>
#include <hip/hip_bf16.h>

// B=4, T=2048, D=1024, H=16, HD=64
#define Bsz 4
#define Tsz 2048
#define Dsz 1024
#define Hsz 16
#define HDsz 64

typedef __attribute__((ext_vector_type(8))) __bf16 bf16x8;
typedef __attribute__((ext_vector_type(4))) __bf16 bf16x4;
typedef __attribute__((ext_vector_type(4))) float f32x4;
typedef __attribute__((ext_vector_type(2))) float f32x2;
typedef unsigned short u16;
typedef unsigned int u32;

#define DEVI static __device__ __forceinline__

DEVI u16 f2bf(float f) {
    __bf16 h = (__bf16)f;
    union { __bf16 h; u16 u; } c; c.h = h; return c.u;
}
DEVI bf16x8 ld_bf8(const u16* p) { return *reinterpret_cast<const bf16x8*>(p); }

// async global->LDS, 16B per lane. lds dest is wave-uniform base + lane*16.
DEVI void gll16(const u16* g, u16* lds) {
    __builtin_amdgcn_global_load_lds(
        (const __attribute__((address_space(1))) u32*)g,
        (__attribute__((address_space(3))) u32*)lds, 16, 0, 0);
}

// K=16 MFMA: acc(16x16, f32) += A(16x16 bf16) * B(16x16 bf16).
DEVI void mfma16(f32x4& c, f32x2 a, f32x2 b) {
    asm("v_mfma_f32_16x16x16_bf16 %0, %1, %2, %0" : "+v"(c) : "v"(a), "v"(b));
}

// ---------------------------------------------------------------------------
// fp32 -> bf16 bulk convert (8 elems/thread, single pass)
// ---------------------------------------------------------------------------
__global__ __launch_bounds__(256)
void conv_bf16(const float* __restrict__ X, u16* __restrict__ Xb)
{
    const size_t i = ((size_t)blockIdx.x * 256 + threadIdx.x) * 8;
    const float4 a = *(const float4*)(X + i);
    const float4 b = *(const float4*)(X + i + 4);
    u16 h[8] = { f2bf(a.x), f2bf(a.y), f2bf(a.z), f2bf(a.w),
                 f2bf(b.x), f2bf(b.y), f2bf(b.z), f2bf(b.w) };
    *(uint4*)(Xb + i) = *(uint4*)h;
}

// ---------------------------------------------------------------------------
// Transpose+convert: W[K][N] fp32 -> WT[N][K] bf16. 64x64 tiles.
// ---------------------------------------------------------------------------
__global__ __launch_bounds__(256)
void transpose_w(const float* __restrict__ W, u16* __restrict__ WT, int K, int N)
{
    __shared__ float tile[64][65];
    const int n0 = blockIdx.x * 64, k0 = blockIdx.y * 64;
    const int t = threadIdx.x;
    #pragma unroll
    for (int i = 0; i < 4; ++i) {
        const int idx = i*256 + t;
        const int row = idx >> 4, c4 = (idx & 15) * 4;
        const float4 v = *(const float4*)(W + (size_t)(k0 + row)*N + n0 + c4);
        tile[row][c4+0] = v.x; tile[row][c4+1] = v.y;
        tile[row][c4+2] = v.z; tile[row][c4+3] = v.w;
    }
    __syncthreads();
    #pragma unroll
    for (int j = 0; j < 2; ++j) {
        const int idx = j*256 + t;
        const int nr = idx >> 3, kc = (idx & 7) * 8;
        u16 h[8];
        #pragma unroll
        for (int e = 0; e < 8; ++e) h[e] = f2bf(tile[kc + e][nr]);
        *(uint4*)(WT + (size_t)(n0 + nr)*K + k0 + kc) = *(uint4*)h;
    }
}

// ---------------------------------------------------------------------------
// 128x128 bf16 MFMA GEMM, BK=32, 4 waves, 4x4 frags/wave.
// 3-deep LDS pipeline + counted s_waitcnt vmcnt(4) + raw s_barrier: tile i+1's
// 4 staging loads stay in flight across the barrier (never drain to 0).
// Exactly 4 vmem ops per k-step -> vmcnt count is exact.
// Safety: all step i-1 ds_reads complete (lgkm before MFMA) before any wave
// reaches barrier i; STAGE target (i+2)%3 is the buffer last read in i-1.
// 1D grid with bijective XCD chunking (nwg % 8 == 0), tN fastest.
// LDS XOR-swizzle (chunk ^= (row>>1)&3), pre-swizzled source.
// ---------------------------------------------------------------------------
template<int EPI>
__global__ __launch_bounds__(256, 3)
void gemm128(const u16* __restrict__ A, const u16* __restrict__ Bt,
             const float* __restrict__ bias, float* __restrict__ Cf,
             u16* __restrict__ Qo, u16* __restrict__ Ko, u16* __restrict__ Vo,
             int M, int N, int K)
{
    __shared__ u16 As[3][128][32];
    __shared__ u16 Bs[3][128][32];

    const int nx  = N >> 7;
    const int nwg = (int)gridDim.x;           // % 8 == 0
    const int cpx = nwg >> 3;
    const int orig = blockIdx.x;
    const int bid  = (orig & 7) * cpx + (orig >> 3);   // XCD-chunked, bijective
    const int tN = bid % nx, tM = bid / nx;

    const int t = threadIdx.x, l = t & 63, w = t >> 6;
    const int wm = w >> 1, wn = w & 1;
    const int lrow = l & 15, lk = l >> 4;

    f32x4 acc[4][4] = {};

    const u16* Ag = A  + (size_t)tM * 128 * K;
    const u16* Bg = Bt + (size_t)tN * 128 * K;

    int srow[2], sch[2];
    #pragma unroll
    for (int r = 0; r < 2; ++r) {
        const int c = r*256 + t;
        srow[r] = c >> 2;
        sch[r]  = (c & 3) ^ ((srow[r] >> 1) & 3);
    }
    const size_t ldso = (size_t)(t & 192) * 8;

    #define STAGE(buf, ks)                                                      \
        {                                                                       \
            _Pragma("unroll")                                                   \
            for (int r = 0; r < 2; ++r) {                                       \
                gll16(Ag + (size_t)srow[r]*K + (ks) + sch[r]*8,                 \
                      &As[buf][0][0] + (size_t)r*2048 + ldso);                  \
                gll16(Bg + (size_t)srow[r]*K + (ks) + sch[r]*8,                 \
                      &Bs[buf][0][0] + (size_t)r*2048 + ldso);                  \
            }                                                                   \
        }

    STAGE(0, 0);
    STAGE(1, 32);

    const int nk = K >> 5;                    // 32
    int cur = 0;
    for (int i = 0; i < nk; ++i) {
        asm volatile("s_waitcnt vmcnt(4)" ::: "memory");   // tile i landed; i+1 in flight
        __builtin_amdgcn_sched_barrier(0);
        __builtin_amdgcn_s_barrier();

        bf16x8 a[4], bb[4];
        #pragma unroll
        for (int ii = 0; ii < 4; ++ii) {
            const int ar = wm*64 + ii*16 + lrow;
            a[ii] = ld_bf8(&As[cur][ar][(lk ^ ((ar >> 1) & 3)) * 8]);
        }
        #pragma unroll
        for (int j = 0; j < 4; ++j) {
            const int br = wn*64 + j*16 + lrow;
            bb[j] = ld_bf8(&Bs[cur][br][(lk ^ ((br >> 1) & 3)) * 8]);
        }

        if (i + 2 < nk) {
            const int nb = (cur + 2) - ((cur + 2) >= 3 ? 3 : 0);
            STAGE(nb, (i + 2) * 32);
        }

        __builtin_amdgcn_s_setprio(1);
        #pragma unroll
        for (int ii = 0; ii < 4; ++ii)
        #pragma unroll
        for (int j = 0; j < 4; ++j)
            acc[ii][j] = __builtin_amdgcn_mfma_f32_16x16x32_bf16(a[ii], bb[j], acc[ii][j], 0, 0, 0);
        __builtin_amdgcn_s_setprio(0);

        cur = (cur + 1) - ((cur + 1) >= 3 ? 3 : 0);
    }
    #undef STAGE

    #pragma unroll
    for (int i = 0; i < 4; ++i)
    #pragma unroll
    for (int j = 0; j < 4; ++j)
    #pragma unroll
    for (int r = 0; r < 4; ++r) {
        const int row = tM*128 + wm*64 + i*16 + lk*4 + r;
        const int col = tN*128 + wn*64 + j*16 + lrow;
        const float v = acc[i][j][r] + bias[col];
        if (EPI == 0) {
            Cf[(size_t)row * N + col] = v;
        } else {
            const int which = col >> 10;
            const int h  = (col & 1023) >> 6;
            const int hd = col & 63;
            const int b  = row >> 11;
            const int tt = row & 2047;
            const int bh = b * Hsz + h;
            const u16 bv = f2bf(v);
            if (which == 0)      Qo[((size_t)bh * Tsz + tt) * HDsz + hd] = bv;
            else if (which == 1) Ko[((size_t)bh * Tsz + tt) * HDsz + hd] = bv;
            else                 Vo[((size_t)bh * HDsz + hd) * Tsz + tt] = bv;
        }
    }
}

// ---------------------------------------------------------------------------
// Flash attention v4 (causal). 4 waves x 32 q-rows; KVBLK=64, double-buffered.
// P stays in registers (16x16x16 PV). Defer-max. Per-CU balanced qt swizzle.
// ---------------------------------------------------------------------------
__global__ __launch_bounds__(256, 4)
void attn3(const u16* __restrict__ Q, const u16* __restrict__ K,
           const u16* __restrict__ Vt, u16* __restrict__ AO)
{
    __shared__ u16 KV[2][2][64][64];   // [buf][K/V][row][col], 32 KB

    const int y = blockIdx.y;                       // bh
    const int x = blockIdx.x;                       // 0..15
    const int idx = (x + (y >> 4)) & 15;
    const int qt = (idx & 1) ? (idx >> 1) : (15 - (idx >> 1));
    const int bh = y;
    const int t = threadIdx.x, w = t >> 6, l = t & 63;
    const int lrow = l & 15, lk = l >> 4;
    const int qw = qt*128 + w*32;
    const int qwmax = qw + 31;
    const int swz = lrow & 7;

    const u16* Qh = Q  + (size_t)bh * Tsz * HDsz;
    const u16* Kh = K  + (size_t)bh * Tsz * HDsz;
    const u16* Vh = Vt + (size_t)bh * HDsz * Tsz;

    bf16x8 qf[2][2];
    #pragma unroll
    for (int f = 0; f < 2; ++f)
    #pragma unroll
    for (int kh = 0; kh < 2; ++kh)
        qf[f][kh] = ld_bf8(&Qh[(size_t)(qw + f*16 + lrow)*HDsz + kh*32 + lk*8]);

    f32x4 o[2][4] = {};
    float m[2] = {-3e38f, -3e38f}, lsum[2] = {0.f, 0.f};

    const int ntile = 2*qt + 2;
    int cur = 0;

    #pragma unroll
    for (int rr = 0; rr < 2; ++rr) {
        const int c = rr*256 + t;
        const int row = c >> 3, gc = (c & 7) ^ (row & 7);
        gll16(Kh + (size_t)row*HDsz + gc*8,
              &KV[0][0][0][0] + (size_t)(rr*256 + (t & 192))*8);
        gll16(Vh + (size_t)row*Tsz + gc*8,
              &KV[0][1][0][0] + (size_t)(rr*256 + (t & 192))*8);
    }
    __syncthreads();

    for (int tk = 0; tk < ntile; ++tk) {
        if (tk + 1 < ntile) {
            const int nkv = (tk + 1) * 64;
            #pragma unroll
            for (int rr = 0; rr < 2; ++rr) {
                const int c = rr*256 + t;
                const int row = c >> 3, gc = (c & 7) ^ (row & 7);
                gll16(Kh + (size_t)(nkv + row)*HDsz + gc*8,
                      &KV[cur^1][0][0][0] + (size_t)(rr*256 + (t & 192))*8);
                gll16(Vh + (size_t)row*Tsz + nkv + gc*8,
                      &KV[cur^1][1][0][0] + (size_t)(rr*256 + (t & 192))*8);
            }
        }
        const int kv0 = tk * 64;
        if (kv0 <= qwmax) {
            const u16 (*Ks)[64] = KV[cur][0];
            const u16 (*Vs)[64] = KV[cur][1];
            const bool fullc    = (kv0 + 63 <= qwmax);
            const bool needmask = (kv0 + 63 > qw);

            f32x4 s[2][4];
            __builtin_amdgcn_s_setprio(1);
            #pragma unroll
            for (int c = 0; c < 4; ++c) {
                if (c >= 2 && !fullc) continue;
                const bf16x8 k0 = ld_bf8(&Ks[c*16 + lrow][((0 + lk) ^ swz) * 8]);
                const bf16x8 k1 = ld_bf8(&Ks[c*16 + lrow][((4 + lk) ^ swz) * 8]);
                #pragma unroll
                for (int f = 0; f < 2; ++f) {
                    f32x4 z = {};
                    z = __builtin_amdgcn_mfma_f32_16x16x32_bf16(k0, qf[f][0], z, 0, 0, 0);
                    z = __builtin_amdgcn_mfma_f32_16x16x32_bf16(k1, qf[f][1], z, 0, 0, 0);
                    s[f][c] = z;
                }
            }
            __builtin_amdgcn_s_setprio(0);

            #pragma unroll
            for (int f = 0; f < 2; ++f) {
                const int q = qw + f*16 + lrow;
                if (needmask) {
                    #pragma unroll
                    for (int c = 0; c < 4; ++c) {
                        if (c >= 2 && !fullc) continue;
                        const int base = kv0 + c*16 + lk*4;
                        #pragma unroll
                        for (int r = 0; r < 4; ++r)
                            if (base + r > q) s[f][c][r] = -1e30f;
                    }
                }
                f32x4 t01;
                #pragma unroll
                for (int r = 0; r < 4; ++r) {
                    t01[r] = fmaxf(s[f][0][r], s[f][1][r]);
                    if (fullc) t01[r] = fmaxf(t01[r], fmaxf(s[f][2][r], s[f][3][r]));
                }
                float mx = fmaxf(fmaxf(t01[0], t01[1]), fmaxf(t01[2], t01[3]));
                mx = fmaxf(mx, __shfl_xor(mx, 16));
                mx = fmaxf(mx, __shfl_xor(mx, 32));
                if (__any(mx > m[f] + 64.f)) {          // defer-max (THR=8 scaled)
                    const float mn = fmaxf(m[f], mx);
                    const float al = __expf((m[f] - mn) * 0.125f);
                    lsum[f] *= al;
                    m[f] = mn;
                    #pragma unroll
                    for (int c = 0; c < 4; ++c)
                    #pragma unroll
                    for (int r = 0; r < 4; ++r) o[f][c][r] *= al;
                }
                const float nm8 = -m[f] * 0.125f;
                f32x4 ps4 = {};
                #pragma unroll
                for (int c = 0; c < 4; ++c) {
                    if (c >= 2 && !fullc) continue;
                    #pragma unroll
                    for (int r = 0; r < 4; ++r) {
                        const float p = __expf(fmaf(s[f][c][r], 0.125f, nm8));
                        s[f][c][r] = p;
                        ps4[r] += p;
                    }
                }
                float ps = (ps4[0] + ps4[1]) + (ps4[2] + ps4[3]);
                ps += __shfl_xor(ps, 16);
                ps += __shfl_xor(ps, 32);
                lsum[f] += ps;
            }

            __builtin_amdgcn_s_setprio(1);
            #pragma unroll
            for (int c = 0; c < 4; ++c) {
                if (c >= 2 && !fullc) continue;
                union { bf16x4 v; f32x2 f; } p0, p1;
                #pragma unroll
                for (int r = 0; r < 4; ++r) {
                    p0.v[r] = (__bf16)s[0][c][r];
                    p1.v[r] = (__bf16)s[1][c][r];
                }
                #pragma unroll
                for (int chd = 0; chd < 4; ++chd) {
                    const f32x2 va = *reinterpret_cast<const f32x2*>(
                        &Vs[chd*16 + lrow][(((c*2 + (lk >> 1)) ^ swz) << 3) + ((lk & 1) << 2)]);
                    mfma16(o[0][chd], va, p0.f);
                    mfma16(o[1][chd], va, p1.f);
                }
            }
            __builtin_amdgcn_s_setprio(0);
        }
        __syncthreads();
        cur ^= 1;
    }

    const int b = bh >> 4, h = bh & 15;
    #pragma unroll
    for (int f = 0; f < 2; ++f) {
        const float rl = 1.0f / lsum[f];
        #pragma unroll
        for (int chd = 0; chd < 4; ++chd) {
            u16 ov[4] = { f2bf(o[f][chd][0]*rl), f2bf(o[f][chd][1]*rl),
                          f2bf(o[f][chd][2]*rl), f2bf(o[f][chd][3]*rl) };
            *(ushort4*)(AO + ((size_t)(b*Tsz + qw + f*16 + lrow))*Dsz
                           + h*HDsz + chd*16 + lk*4) = *(ushort4*)ov;
        }
    }
}

extern "C" void kernel_launch(void* const* d_in, const int* in_sizes, int n_in,
                              void* d_out, int out_size, void* d_ws, size_t ws_size,
                              hipStream_t stream)
{
    (void)in_sizes; (void)n_in; (void)out_size; (void)ws_size;

    const float* x      = (const float*)d_in[0];
    const float* qkv_w  = (const float*)d_in[1];
    const float* qkv_b  = (const float*)d_in[2];
    const float* proj_w = (const float*)d_in[3];
    const float* proj_b = (const float*)d_in[4];
    float* out = (float*)d_out;

    char* ws = (char*)d_ws;
    const size_t SZ = (size_t)Bsz * Hsz * Tsz * HDsz * sizeof(u16);  // 16 MB
    u16* R0 = (u16*)(ws);
    u16* Qb = (u16*)(ws + SZ);
    u16* Kb = (u16*)(ws + 2*SZ);
    u16* Vt = (u16*)(ws + 3*SZ);
    u16* WQKVT = R0;          // dead after QKV GEMM
    u16* AO    = R0;          // reuses WQKVT region
    u16* WPT   = Qb;          // reuses Q region after attention

    // x as bf16, staged in d_out's first 16.8 MB (out is 33.5 MB fp32,
    // fully overwritten by the proj GEMM at the end -> safe scratch).
    u16* Xb = (u16*)d_out;

    const int M = Bsz * Tsz;  // 8192

    conv_bf16<<<(M*Dsz)/(256*8), 256, 0, stream>>>(x, Xb);
    transpose_w<<<dim3(3*Dsz/64, Dsz/64), 256, 0, stream>>>(qkv_w, WQKVT, Dsz, 3*Dsz);
    gemm128<1><<<dim3((3*Dsz/128) * (M/128)), 256, 0, stream>>>(
        Xb, WQKVT, qkv_b, nullptr, Qb, Kb, Vt, M, 3*Dsz, Dsz);
    attn3<<<dim3(Tsz/128, Bsz*Hsz), 256, 0, stream>>>(Qb, Kb, Vt, AO);
    transpose_w<<<dim3(Dsz/64, Dsz/64), 256, 0, stream>>>(proj_w, WPT, Dsz, Dsz);
    gemm128<0><<<dim3((Dsz/128) * (M/128)), 256, 0, stream>>>(
        AO, WPT, proj_b, out, nullptr, nullptr, nullptr, M, Dsz, Dsz);
}